// Round 9
// baseline (214.625 us; speedup 1.0000x reference)
//
#include <hip/hip_runtime.h>
#include <hip/hip_bf16.h>

// Problem constants
#define BB 2
#define SS 2048
#define GG 16
#define HH 8
#define EE 64
#define DD 512
#define NCHUNK 32
#define CLEN 64
#define CS_STRIDE 132  // 64 sk + 64 sv + 1 n + 3 pad

typedef __attribute__((ext_vector_type(8))) short bf16x8;
typedef __attribute__((ext_vector_type(4))) short s16x4;
typedef __attribute__((ext_vector_type(4))) float f32x4;

static __device__ __forceinline__ short f2bf(float x) {
  union { float f; unsigned u; } v; v.f = x;
  unsigned r = v.u + 0x7fffu + ((v.u >> 16) & 1u);  // round-nearest-even
  return (short)(r >> 16);
}
static __device__ __forceinline__ float bf2f(short s) {
  return __uint_as_float(((unsigned)(unsigned short)s) << 16);
}
static __device__ __forceinline__ void bsplit(float x, short& hi, short& lo) {
  hi = f2bf(x);
  lo = f2bf(x - bf2f(hi));
}

// ---- prep kernel: z<4 weight transpose+cvt; z==4 ctx split-K partials; z>=5 f32->bf16 cvt ----
__global__ __launch_bounds__(256) void prep_kernel(const float* __restrict__ w0,
                                                   const float* __restrict__ w1,
                                                   const float* __restrict__ w2,
                                                   const float* __restrict__ w3,
                                                   short* __restrict__ o0,
                                                   short* __restrict__ o1,
                                                   short* __restrict__ o2,
                                                   short* __restrict__ o3,
                                                   const float* __restrict__ ctxA,
                                                   const float* __restrict__ ctxW,
                                                   float* __restrict__ part,
                                                   const float* __restrict__ qin,
                                                   const float* __restrict__ kin,
                                                   const float* __restrict__ vin,
                                                   short* __restrict__ Qb,
                                                   short* __restrict__ Kb,
                                                   short* __restrict__ Vb) {
  __shared__ float smem[32 * 68 + 64 * 68];
  const int tx = threadIdx.x, ty = threadIdx.y;
  const int tid = ty * 32 + tx;
  if (blockIdx.z < 4) {
    const float* W; short* O;
    if (blockIdx.z == 0)      { W = w0; O = o0; }
    else if (blockIdx.z == 1) { W = w1; O = o1; }
    else if (blockIdx.z == 2) { W = w2; O = o2; }
    else                      { W = w3; O = o3; }
    float (*t)[33] = (float (*)[33])smem;
    const int k0 = blockIdx.x * 32, n0 = blockIdx.y * 32;
#pragma unroll
    for (int i = 0; i < 4; ++i)
      t[ty + i * 8][tx] = W[(size_t)(k0 + ty + i * 8) * DD + n0 + tx];
    __syncthreads();
#pragma unroll
    for (int i = 0; i < 4; ++i)
      O[(size_t)(n0 + ty + i * 8) * DD + k0 + tx] = f2bf(t[tx][ty + i * 8]);
    return;
  }
  if (blockIdx.z >= 5) {
    const float* src; short* dst;
    if (blockIdx.z == 5)      { src = qin; dst = Qb; }
    else if (blockIdx.z == 6) { src = kin; dst = Kb; }
    else                      { src = vin; dst = Vb; }
    const size_t base0 = (size_t)(blockIdx.y * 16 + blockIdx.x) * 8192 + tid * 8;
#pragma unroll
    for (int i = 0; i < 4; ++i) {
      size_t base = base0 + (size_t)i * 2048;
      float4 x0 = *(const float4*)(src + base);
      float4 x1 = *(const float4*)(src + base + 4);
      bf16x8 o;
      o[0] = f2bf(x0.x); o[1] = f2bf(x0.y); o[2] = f2bf(x0.z); o[3] = f2bf(x0.w);
      o[4] = f2bf(x1.x); o[5] = f2bf(x1.y); o[6] = f2bf(x1.z); o[7] = f2bf(x1.w);
      *(bf16x8*)(dst + base) = o;
    }
    return;
  }
  if (blockIdx.x >= 8 || blockIdx.y >= 8) return;
  const int nt = blockIdx.x, ky = blockIdx.y;
  float (*As)[68] = (float (*)[68])smem;
  float (*Ws)[68] = (float (*)[68])(smem + 32 * 68);
  {
    int m = tid >> 3, kq = (tid & 7) * 8;
    float4 a0 = *(const float4*)(ctxA + (size_t)m * DD + ky * 64 + kq);
    float4 a1 = *(const float4*)(ctxA + (size_t)m * DD + ky * 64 + kq + 4);
    As[m][kq + 0] = a0.x; As[m][kq + 1] = a0.y; As[m][kq + 2] = a0.z; As[m][kq + 3] = a0.w;
    As[m][kq + 4] = a1.x; As[m][kq + 5] = a1.y; As[m][kq + 6] = a1.z; As[m][kq + 7] = a1.w;
  }
  {
    int k = tid >> 2, nq = (tid & 3) * 16;
#pragma unroll
    for (int i = 0; i < 4; ++i) {
      float4 wv = *(const float4*)(ctxW + (size_t)(ky * 64 + k) * DD + nt * 64 + nq + i * 4);
      Ws[k][nq + i * 4 + 0] = wv.x; Ws[k][nq + i * 4 + 1] = wv.y;
      Ws[k][nq + i * 4 + 2] = wv.z; Ws[k][nq + i * 4 + 3] = wv.w;
    }
  }
  __syncthreads();
  const int txl = tid & 63, my = tid >> 6;
  float acc[8] = {};
  for (int k = 0; k < 64; ++k) {
    float wv = Ws[k][txl];
#pragma unroll
    for (int m = 0; m < 8; ++m) acc[m] += As[my * 8 + m][k] * wv;
  }
#pragma unroll
  for (int m = 0; m < 8; ++m)
    part[((size_t)ky * 32 + my * 8 + m) * DD + nt * 64 + txl] = acc[m];
}

#define LDA 72

// ---- batched projection GEMM (bf16 A), 64x128 tile, BK=64; hi/lo planes out ----
// DIAGNOSTIC: reps>1 repeats the full accumulation (identical result) to amplify
// this kernel's duration past the harness fills so its counters appear in top-5.
__global__ __launch_bounds__(256) void proj_gemm(const short* __restrict__ a0,
                                                 const short* __restrict__ a1,
                                                 const short* __restrict__ a2,
                                                 const short* __restrict__ b0,
                                                 const short* __restrict__ b1,
                                                 const short* __restrict__ b2,
                                                 short* __restrict__ h0,
                                                 short* __restrict__ l0,
                                                 short* __restrict__ h1,
                                                 short* __restrict__ l1,
                                                 short* __restrict__ h2,
                                                 int reps) {
  const short* A; const short* Bt; short* Chi; short* Clo;
  if (blockIdx.z == 0)      { A = a0; Bt = b0; Chi = h0; Clo = l0; }
  else if (blockIdx.z == 1) { A = a1; Bt = b1; Chi = h1; Clo = l1; }
  else                      { A = a2; Bt = b2; Chi = h2; Clo = nullptr; }
  const int N = DD, K = DD;
  __shared__ short As[64 * LDA];
  __shared__ short Bs[128 * LDA];
  const int tid = threadIdx.x;
  const int m0 = blockIdx.y * 64, n0 = blockIdx.x * 128;
  const int wv = tid >> 6, lane = tid & 63;
  const int wm = wv * 16;
  const int r = lane & 15, q = lane >> 4;
  f32x4 acc[8];
  for (int rep = 0; rep < reps; ++rep) {
#pragma unroll
    for (int j = 0; j < 8; ++j) acc[j] = (f32x4){0.f, 0.f, 0.f, 0.f};
    for (int k0 = 0; k0 < K; k0 += 64) {
      bf16x8 av[2], bvv[4];
#pragma unroll
      for (int it = 0; it < 2; ++it) {
        int idx = tid + it * 256;
        int row = idx >> 3, colq = (idx & 7) * 8;
        av[it] = *(const bf16x8*)(A + (size_t)(m0 + row) * K + k0 + colq);
      }
#pragma unroll
      for (int it = 0; it < 4; ++it) {
        int idx = tid + it * 256;
        int row = idx >> 3, colq = (idx & 7) * 8;
        bvv[it] = *(const bf16x8*)(Bt + (size_t)(n0 + row) * K + k0 + colq);
      }
      __syncthreads();
#pragma unroll
      for (int it = 0; it < 2; ++it) {
        int idx = tid + it * 256;
        int row = idx >> 3, colq = (idx & 7) * 8;
        *(bf16x8*)(&As[row * LDA + colq]) = av[it];
      }
#pragma unroll
      for (int it = 0; it < 4; ++it) {
        int idx = tid + it * 256;
        int row = idx >> 3, colq = (idx & 7) * 8;
        *(bf16x8*)(&Bs[row * LDA + colq]) = bvv[it];
      }
      __syncthreads();
#pragma unroll
      for (int ks = 0; ks < 2; ++ks) {
        bf16x8 a0r = *(const bf16x8*)(&As[(wm + r) * LDA + ks * 32 + q * 8]);
#pragma unroll
        for (int j = 0; j < 8; ++j) {
          bf16x8 br = *(const bf16x8*)(&Bs[(j * 16 + r) * LDA + ks * 32 + q * 8]);
          acc[j] = __builtin_amdgcn_mfma_f32_16x16x32_bf16(a0r, br, acc[j], 0, 0, 0);
        }
      }
    }
  }
#pragma unroll
  for (int j = 0; j < 8; ++j)
#pragma unroll
    for (int reg = 0; reg < 4; ++reg) {
      int m = m0 + wm + q * 4 + reg;
      int n = n0 + j * 16 + r;
      float x = acc[j][reg];
      short hi = f2bf(x);
      Chi[(size_t)m * N + n] = hi;
      if (Clo) Clo[(size_t)m * N + n] = f2bf(x - bf2f(hi));
    }
}

// ---------------- output GEMM (bf16 A), 64x128 tile, BK=64 ----------------
__global__ __launch_bounds__(256) void gemm_bf16(const short* __restrict__ A,
                                                 const short* __restrict__ Bt,
                                                 float* __restrict__ C,
                                                 int M, int N, int K) {
  __shared__ short As[64 * LDA];
  __shared__ short Bs[128 * LDA];
  const int tid = threadIdx.x;
  const int m0 = blockIdx.y * 64, n0 = blockIdx.x * 128;
  const int wv = tid >> 6, lane = tid & 63;
  const int wm = wv * 16;
  const int r = lane & 15, q = lane >> 4;
  f32x4 acc[8] = {};
  for (int k0 = 0; k0 < K; k0 += 64) {
    bf16x8 av[2], bvv[4];
#pragma unroll
    for (int it = 0; it < 2; ++it) {
      int idx = tid + it * 256;
      int row = idx >> 3, colq = (idx & 7) * 8;
      av[it] = *(const bf16x8*)(A + (size_t)(m0 + row) * K + k0 + colq);
    }
#pragma unroll
    for (int it = 0; it < 4; ++it) {
      int idx = tid + it * 256;
      int row = idx >> 3, colq = (idx & 7) * 8;
      bvv[it] = *(const bf16x8*)(Bt + (size_t)(n0 + row) * K + k0 + colq);
    }
    __syncthreads();
#pragma unroll
    for (int it = 0; it < 2; ++it) {
      int idx = tid + it * 256;
      int row = idx >> 3, colq = (idx & 7) * 8;
      *(bf16x8*)(&As[row * LDA + colq]) = av[it];
    }
#pragma unroll
    for (int it = 0; it < 4; ++it) {
      int idx = tid + it * 256;
      int row = idx >> 3, colq = (idx & 7) * 8;
      *(bf16x8*)(&Bs[row * LDA + colq]) = bvv[it];
    }
    __syncthreads();
#pragma unroll
    for (int ks = 0; ks < 2; ++ks) {
      bf16x8 a0r = *(const bf16x8*)(&As[(wm + r) * LDA + ks * 32 + q * 8]);
#pragma unroll
      for (int j = 0; j < 8; ++j) {
        bf16x8 br = *(const bf16x8*)(&Bs[(j * 16 + r) * LDA + ks * 32 + q * 8]);
        acc[j] = __builtin_amdgcn_mfma_f32_16x16x32_bf16(a0r, br, acc[j], 0, 0, 0);
      }
    }
  }
#pragma unroll
  for (int j = 0; j < 8; ++j)
#pragma unroll
    for (int reg = 0; reg < 4; ++reg) {
      int m = m0 + wm + q * 4 + reg;
      int n = n0 + j * 16 + r;
      C[(size_t)m * N + n] = acc[j][reg];
    }
}

#define LDW 72
#define LDN 40

// ---------------- scan phase A: chunk-local sums via MFMA; also exports w planes ----------------
__global__ __launch_bounds__(256) void scanA_kernel(const short* __restrict__ Kh,
                                                    const short* __restrict__ Kl,
                                                    const short* __restrict__ Vb,
                                                    const float* __restrict__ part,
                                                    float* __restrict__ csums,
                                                    short* __restrict__ wG) {
  const int bh = blockIdx.y, c = blockIdx.x;
  const int b = bh >> 3, h = bh & 7;
  const int tid = threadIdx.x;
  const int lane = tid & 63, wvid = tid >> 6;
  const int r = lane & 15, q = lane >> 4;

  __shared__ short csh[16 * LDW], csl[16 * LDW];
  __shared__ short kh[64 * LDW], kl[64 * LDW];
  __shared__ short kTh[64 * LDW], kTl[64 * LDW];
  __shared__ short vT[64 * LDW];
  __shared__ short wh[16 * LDW], wl[16 * LDW];
  __shared__ float nPart[4][16];

  const int row = tid >> 2, c16 = (tid & 3) * 16;
  const size_t gb = ((size_t)(b * SS + c * CLEN + row)) * DD + h * EE + c16;
  bf16x8 kh0 = *(const bf16x8*)(Kh + gb);
  bf16x8 kh1 = *(const bf16x8*)(Kh + gb + 8);
  bf16x8 kl0 = *(const bf16x8*)(Kl + gb);
  bf16x8 kl1 = *(const bf16x8*)(Kl + gb + 8);
  bf16x8 v0 = *(const bf16x8*)(Vb + gb);
  bf16x8 v1 = *(const bf16x8*)(Vb + gb + 8);
  *(bf16x8*)(&kh[row * LDW + c16]) = kh0;
  *(bf16x8*)(&kh[row * LDW + c16 + 8]) = kh1;
  *(bf16x8*)(&kl[row * LDW + c16]) = kl0;
  *(bf16x8*)(&kl[row * LDW + c16 + 8]) = kl1;
#pragma unroll
  for (int t = 0; t < 8; ++t) {
    kTh[(c16 + t) * LDW + row] = kh0[t];
    kTh[(c16 + 8 + t) * LDW + row] = kh1[t];
    kTl[(c16 + t) * LDW + row] = kl0[t];
    kTl[(c16 + 8 + t) * LDW + row] = kl1[t];
    vT[(c16 + t) * LDW + row] = v0[t];
    vT[(c16 + 8 + t) * LDW + row] = v1[t];
  }
  {
    const int g0 = tid >> 4, t4 = (tid & 15) * 4;
    float4 csv = make_float4(0, 0, 0, 0);
#pragma unroll
    for (int ky = 0; ky < 8; ++ky) {
      float4 p = *(const float4*)(part + ((size_t)(ky * 32 + b * GG + g0)) * DD + h * EE + t4);
      csv.x += p.x; csv.y += p.y; csv.z += p.z; csv.w += p.w;
    }
    const float* pc = (const float*)&csv;
#pragma unroll
    for (int e = 0; e < 4; ++e) {
      short hi, lo;
      bsplit(pc[e], hi, lo);
      csh[g0 * LDW + t4 + e] = hi;
      csl[g0 * LDW + t4 + e] = lo;
    }
  }
  __syncthreads();  // S0

  f32x4 accw = {0.f, 0.f, 0.f, 0.f};
#pragma unroll
  for (int ks = 0; ks < 2; ++ks) {
    bf16x8 ah = *(const bf16x8*)(&csh[r * LDW + ks * 32 + q * 8]);
    bf16x8 al = *(const bf16x8*)(&csl[r * LDW + ks * 32 + q * 8]);
    bf16x8 bh = *(const bf16x8*)(&kh[(wvid * 16 + r) * LDW + ks * 32 + q * 8]);
    bf16x8 bl = *(const bf16x8*)(&kl[(wvid * 16 + r) * LDW + ks * 32 + q * 8]);
    accw = __builtin_amdgcn_mfma_f32_16x16x32_bf16(ah, bh, accw, 0, 0, 0);
    accw = __builtin_amdgcn_mfma_f32_16x16x32_bf16(ah, bl, accw, 0, 0, 0);
    accw = __builtin_amdgcn_mfma_f32_16x16x32_bf16(al, bh, accw, 0, 0, 0);
  }
  const size_t wbase = (size_t)(bh * NCHUNK + c) * 2048;
  float wf[4];
#pragma unroll
  for (int reg = 0; reg < 4; ++reg) {
    wf[reg] = expf(accw[reg] * 0.125f);
    short hi, lo;
    bsplit(wf[reg], hi, lo);
    int g = q * 4 + reg, t = wvid * 16 + r;
    wh[g * LDW + t] = hi;
    wl[g * LDW + t] = lo;
    wG[wbase + g * 64 + t] = hi;          // export w hi plane
    wG[wbase + 1024 + g * 64 + t] = lo;   // export w lo plane
  }
#pragma unroll
  for (int reg = 0; reg < 4; ++reg) {
    float np = wf[reg];
    np += __shfl_xor(np, 1);
    np += __shfl_xor(np, 2);
    np += __shfl_xor(np, 4);
    np += __shfl_xor(np, 8);
    if (r == 0) nPart[wvid][q * 4 + reg] = np;
  }
  __syncthreads();  // S1

  f32x4 ask = {0.f, 0.f, 0.f, 0.f}, asv = ask;
#pragma unroll
  for (int ks = 0; ks < 2; ++ks) {
    bf16x8 awh = *(const bf16x8*)(&wh[r * LDW + ks * 32 + q * 8]);
    bf16x8 awl = *(const bf16x8*)(&wl[r * LDW + ks * 32 + q * 8]);
    bf16x8 bkh = *(const bf16x8*)(&kTh[(wvid * 16 + r) * LDW + ks * 32 + q * 8]);
    bf16x8 bkl = *(const bf16x8*)(&kTl[(wvid * 16 + r) * LDW + ks * 32 + q * 8]);
    bf16x8 bv = *(const bf16x8*)(&vT[(wvid * 16 + r) * LDW + ks * 32 + q * 8]);
    ask = __builtin_amdgcn_mfma_f32_16x16x32_bf16(awh, bkh, ask, 0, 0, 0);
    ask = __builtin_amdgcn_mfma_f32_16x16x32_bf16(awh, bkl, ask, 0, 0, 0);
    ask = __builtin_amdgcn_mfma_f32_16x16x32_bf16(awl, bkh, ask, 0, 0, 0);
    asv = __builtin_amdgcn_mfma_f32_16x16x32_bf16(awh, bv, asv, 0, 0, 0);
    asv = __builtin_amdgcn_mfma_f32_16x16x32_bf16(awl, bv, asv, 0, 0, 0);
  }
#pragma unroll
  for (int reg = 0; reg < 4; ++reg) {
    int g = q * 4 + reg, e = wvid * 16 + r;
    size_t ob = ((size_t)((bh * NCHUNK + c) * GG + g)) * CS_STRIDE;
    csums[ob + e] = ask[reg];
    csums[ob + 64 + e] = asv[reg];
  }
  if (tid < 16) {
    size_t ob = ((size_t)((bh * NCHUNK + c) * GG + tid)) * CS_STRIDE;
    csums[ob + 128] = nPart[0][tid] + nPart[1][tid] + nPart[2][tid] + nPart[3][tid];
  }
}

// ---------------- chunk kernel: causal attention, w loaded (not recomputed) ----------------
__global__ __launch_bounds__(256) void chunk_kernel(const short* __restrict__ Kh,
                                                    const short* __restrict__ Vb,
                                                    const short* __restrict__ Qh,
                                                    const short* __restrict__ Ql,
                                                    const short* __restrict__ wG,
                                                    const float* __restrict__ csums,
                                                    short* __restrict__ attnbf) {
  const int c = blockIdx.x, bh = blockIdx.y;
  const int b = bh >> 3, h = bh & 7;
  const int tid = threadIdx.x;
  const int lane = tid & 63, wvid = tid >> 6;
  const int r = lane & 15, q = lane >> 4;
  const int sw = wvid * 16;

  __shared__ short qh[64 * LDW], qlo[64 * LDW], khb[64 * LDW], dh[64 * LDW];
  __shared__ short whb[16 * LDW], wlb[16 * LDW], skph[16 * LDW], skpl[16 * LDW];
  __shared__ short svpt[64 * LDN];
  __shared__ float nL[16 * 68];
  __shared__ float npreL[16];
  short* wct = qh;   // reused post-B1
  short* cmb = qlo;  // reused post-B1
  short* vt = khb;   // reused post-B1
  short* uh = dh;    // reused post-phase3

  const int row = tid >> 2, c16 = (tid & 3) * 16;
  const size_t gb = ((size_t)(b * SS + c * CLEN + row)) * DD + h * EE + c16;
  bf16x8 q0 = *(const bf16x8*)(Qh + gb);
  bf16x8 q1 = *(const bf16x8*)(Qh + gb + 8);
  bf16x8 ql0 = *(const bf16x8*)(Ql + gb);
  bf16x8 ql1 = *(const bf16x8*)(Ql + gb + 8);
  bf16x8 k0 = *(const bf16x8*)(Kh + gb);
  bf16x8 k1 = *(const bf16x8*)(Kh + gb + 8);
  bf16x8 v0 = *(const bf16x8*)(Vb + gb);
  bf16x8 v1 = *(const bf16x8*)(Vb + gb + 8);
  // w planes (bit-exact values scanA computed)
  const size_t wbase = (size_t)(bh * NCHUNK + c) * 2048;
  s16x4 wh4 = *(const s16x4*)(wG + wbase + tid * 4);
  s16x4 wl4 = *(const s16x4*)(wG + wbase + 1024 + tid * 4);

  const int g0 = tid >> 4, t4 = (tid & 15) * 4;
  float4 skv = make_float4(0, 0, 0, 0), svv = make_float4(0, 0, 0, 0);
  {
    int c2 = 0;
    for (; c2 + 4 <= c; c2 += 4) {
#pragma unroll
      for (int u = 0; u < 4; ++u) {
        size_t ob2 = ((size_t)((bh * NCHUNK + c2 + u) * GG + g0)) * CS_STRIDE;
        float4 a = *(const float4*)(csums + ob2 + t4);
        float4 bsum = *(const float4*)(csums + ob2 + 64 + t4);
        skv.x += a.x; skv.y += a.y; skv.z += a.z; skv.w += a.w;
        svv.x += bsum.x; svv.y += bsum.y; svv.z += bsum.z; svv.w += bsum.w;
      }
    }
    for (; c2 < c; ++c2) {
      size_t ob2 = ((size_t)((bh * NCHUNK + c2) * GG + g0)) * CS_STRIDE;
      float4 a = *(const float4*)(csums + ob2 + t4);
      float4 bsum = *(const float4*)(csums + ob2 + 64 + t4);
      skv.x += a.x; skv.y += a.y; skv.z += a.z; skv.w += a.w;
      svv.x += bsum.x; svv.y += bsum.y; svv.z += bsum.z; svv.w += bsum.w;
    }
  }
  if (tid < 16) {
    float npr = 0.f;
    for (int c2 = 0; c2 < c; ++c2)
      npr += csums[((size_t)((bh * NCHUNK + c2) * GG + tid)) * CS_STRIDE + 128];
    npreL[tid] = npr;
  }

  *(bf16x8*)(&qh[row * LDW + c16]) = q0;
  *(bf16x8*)(&qh[row * LDW + c16 + 8]) = q1;
  *(bf16x8*)(&qlo[row * LDW + c16]) = ql0;
  *(bf16x8*)(&qlo[row * LDW + c16 + 8]) = ql1;
  *(bf16x8*)(&khb[row * LDW + c16]) = k0;
  *(bf16x8*)(&khb[row * LDW + c16 + 8]) = k1;
  {
    // stage w planes: idx = tid*4 -> g = idx>>6, t = idx&63
    int gI = (tid * 4) >> 6, tI = (tid * 4) & 63;
    *(s16x4*)(&whb[gI * LDW + tI]) = wh4;
    *(s16x4*)(&wlb[gI * LDW + tI]) = wl4;
  }
  {
    const float* ps = (const float*)&skv;
#pragma unroll
    for (int e = 0; e < 4; ++e) {
      short hi, lo;
      bsplit(ps[e], hi, lo);
      skph[g0 * LDW + t4 + e] = hi;
      skpl[g0 * LDW + t4 + e] = lo;
    }
  }
  __syncthreads();  // S0

#pragma unroll
  for (int gg = 0; gg < 4; ++gg) {
    int g = wvid * 4 + gg;
    float val = bf2f(whb[g * LDW + lane]) + bf2f(wlb[g * LDW + lane]);
#pragma unroll
    for (int d = 1; d < 64; d <<= 1) {
      float tup = __shfl_up(val, d);
      if (lane >= d) val += tup;
    }
    nL[g * 68 + lane] = npreL[g] + val;
  }

  f32x4 accd[4];
  f32x4 accwt = {0.f, 0.f, 0.f, 0.f};
#pragma unroll
  for (int ct = 0; ct < 4; ++ct) accd[ct] = accwt;
#pragma unroll
  for (int kst = 0; kst < 2; ++kst) {
    bf16x8 aq = *(const bf16x8*)(&qh[(sw + r) * LDW + kst * 32 + q * 8]);
    bf16x8 aql = *(const bf16x8*)(&qlo[(sw + r) * LDW + kst * 32 + q * 8]);
    bf16x8 bsh = *(const bf16x8*)(&skph[r * LDW + kst * 32 + q * 8]);
    bf16x8 bsl = *(const bf16x8*)(&skpl[r * LDW + kst * 32 + q * 8]);
    accwt = __builtin_amdgcn_mfma_f32_16x16x32_bf16(aq, bsh, accwt, 0, 0, 0);
    accwt = __builtin_amdgcn_mfma_f32_16x16x32_bf16(aq, bsl, accwt, 0, 0, 0);
    accwt = __builtin_amdgcn_mfma_f32_16x16x32_bf16(aql, bsh, accwt, 0, 0, 0);
#pragma unroll
    for (int ct = 0; ct < 4; ++ct) {
      bf16x8 bk = *(const bf16x8*)(&khb[(ct * 16 + r) * LDW + kst * 32 + q * 8]);
      accd[ct] = __builtin_amdgcn_mfma_f32_16x16x32_bf16(aq, bk, accd[ct], 0, 0, 0);
    }
  }
#pragma unroll
  for (int ct = 0; ct < 4; ++ct)
#pragma unroll
    for (int reg = 0; reg < 4; ++reg) {
      int sl = sw + q * 4 + reg, tl = ct * 16 + r;
      float v = (tl <= sl) ? accd[ct][reg] : 0.f;
      dh[sl * LDW + tl] = f2bf(v);
    }
  __syncthreads();  // B1

#pragma unroll
  for (int t = 0; t < 8; ++t) {
    vt[(c16 + t) * LDW + row] = v0[t];
    vt[(c16 + 8 + t) * LDW + row] = v1[t];
  }
  {
    const float* pv = (const float*)&svv;
#pragma unroll
    for (int e = 0; e < 4; ++e)
      svpt[(t4 + e) * LDN + g0] = f2bf(pv[e]);
    int ez = tid >> 2, gz = 16 + (tid & 3) * 4;
#pragma unroll
    for (int e = 0; e < 4; ++e) svpt[ez * LDN + gz + e] = 0;
    int tt = tid >> 2, gw = (tid & 3) * 4;
#pragma unroll
    for (int e = 0; e < 4; ++e) {
      wct[tt * LDN + gw + e] = whb[(gw + e) * LDW + tt];
      wct[tt * LDN + 16 + gw + e] = 0;
    }
  }

#pragma unroll
  for (int kst = 0; kst < 2; ++kst) {
    bf16x8 ad = *(const bf16x8*)(&dh[(sw + r) * LDW + kst * 32 + q * 8]);
    bf16x8 bw = *(const bf16x8*)(&whb[r * LDW + kst * 32 + q * 8]);
    bf16x8 bl = *(const bf16x8*)(&wlb[r * LDW + kst * 32 + q * 8]);
    accwt = __builtin_amdgcn_mfma_f32_16x16x32_bf16(ad, bw, accwt, 0, 0, 0);
    accwt = __builtin_amdgcn_mfma_f32_16x16x32_bf16(ad, bl, accwt, 0, 0, 0);
  }
#pragma unroll
  for (int reg = 0; reg < 4; ++reg) {
    int sl = sw + q * 4 + reg;
    float nv = fmaxf(nL[r * 68 + sl], 1e-8f);
    float wt = accwt[reg] / nv;
    float m = wt;
    m = fmaxf(m, __shfl_xor(m, 1));
    m = fmaxf(m, __shfl_xor(m, 2));
    m = fmaxf(m, __shfl_xor(m, 4));
    m = fmaxf(m, __shfl_xor(m, 8));
    float ex = expf(wt - m);
    float den = ex;
    den += __shfl_xor(den, 1);
    den += __shfl_xor(den, 2);
    den += __shfl_xor(den, 4);
    den += __shfl_xor(den, 8);
    float cmv = (ex / den) / nv;
    cmb[sl * LDN + r] = f2bf(cmv);
    cmb[sl * LDN + 16 + r] = 0;
  }
  __syncthreads();  // B2

  bf16x8 acm = *(const bf16x8*)(&cmb[(sw + r) * LDN + q * 8]);
  f32x4 accu[4];
#pragma unroll
  for (int ct = 0; ct < 4; ++ct) accu[ct] = (f32x4){0.f, 0.f, 0.f, 0.f};
#pragma unroll
  for (int ct = 0; ct < 4; ++ct) {
    bf16x8 bwc = *(const bf16x8*)(&wct[(ct * 16 + r) * LDN + q * 8]);
    accu[ct] = __builtin_amdgcn_mfma_f32_16x16x32_bf16(acm, bwc, accu[ct], 0, 0, 0);
  }
#pragma unroll
  for (int ct = 0; ct < 4; ++ct)
#pragma unroll
    for (int reg = 0; reg < 4; ++reg) {
      int sl = sw + q * 4 + reg, tl = ct * 16 + r;
      float v = (tl <= sl) ? accu[ct][reg] : 0.f;
      uh[sl * LDW + tl] = f2bf(v);
    }

  f32x4 acco[4];
#pragma unroll
  for (int et = 0; et < 4; ++et) acco[et] = (f32x4){0.f, 0.f, 0.f, 0.f};
#pragma unroll
  for (int et = 0; et < 4; ++et) {
    bf16x8 bs = *(const bf16x8*)(&svpt[(et * 16 + r) * LDN + q * 8]);
    acco[et] = __builtin_amdgcn_mfma_f32_16x16x32_bf16(acm, bs, acco[et], 0, 0, 0);
  }
#pragma unroll
  for (int kst = 0; kst < 2; ++kst) {
    bf16x8 au = *(const bf16x8*)(&uh[(sw + r) * LDW + kst * 32 + q * 8]);
#pragma unroll
    for (int et = 0; et < 4; ++et) {
      bf16x8 bv = *(const bf16x8*)(&vt[(et * 16 + r) * LDW + kst * 32 + q * 8]);
      acco[et] = __builtin_amdgcn_mfma_f32_16x16x32_bf16(au, bv, acco[et], 0, 0, 0);
    }
  }
#pragma unroll
  for (int et = 0; et < 4; ++et)
#pragma unroll
    for (int reg = 0; reg < 4; ++reg) {
      int sl = sw + q * 4 + reg;
      attnbf[((size_t)(b * SS + c * CLEN + sl)) * DD + h * EE + et * 16 + r] =
          f2bf(acco[et][reg]);
    }
}

extern "C" void kernel_launch(void* const* d_in, const int* in_sizes, int n_in,
                              void* d_out, int out_size, void* d_ws, size_t ws_size,
                              hipStream_t stream) {
  const float* query = (const float*)d_in[0];
  const float* key = (const float*)d_in[1];
  const float* value = (const float*)d_in[2];
  const float* context = (const float*)d_in[3];
  const float* query_proj = (const float*)d_in[4];
  const float* key_proj = (const float*)d_in[5];
  const float* value_proj = (const float*)d_in[6];
  const float* output_proj = (const float*)d_in[7];
  const float* context_proj = (const float*)d_in[8];
  float* out = (float*)d_out;

  const size_t MS = (size_t)BB * SS * DD;  // 2M elements
  const size_t CSN = (size_t)BB * HH * NCHUNK * GG * CS_STRIDE;
  float* fbase = (float*)d_ws;
  float* csums = fbase;                 // 8192*132
  float* part = csums + CSN;            // 8*32*512
  short* Qh = (short*)(part + (size_t)8 * 32 * DD);
  short* Ql = Qh + MS;
  short* Kh = Ql + MS;
  short* Kl = Kh + MS;
  short* Vb = Kl + MS;
  short* Abf = Vb + MS;  // attn bf16
  short* Wq = Abf + MS;
  short* Wk = Wq + (size_t)DD * DD;
  short* Wv = Wk + (size_t)DD * DD;
  short* Wo = Wv + (size_t)DD * DD;
  short* Qbin = Wo + (size_t)DD * DD;   // bf16 raw activations
  short* Kbin = Qbin + MS;
  short* Vbin = Kbin + MS;
  short* wGp = Vbin + MS;               // w hi/lo planes: 512 blocks x 2048 shorts

  dim3 blk(256);
  dim3 tb(32, 8);

  prep_kernel<<<dim3(16, 16, 8), tb, 0, stream>>>(
      query_proj, key_proj, value_proj, output_proj, Wq, Wk, Wv, Wo,
      context, context_proj, part, query, key, value, Qbin, Kbin, Vbin);

  // DIAGNOSTIC round: reps=8 amplifies proj_gemm so its counters surface in top-5.
  proj_gemm<<<dim3(DD / 128, (BB * SS) / 64, 3), blk, 0, stream>>>(
      Qbin, Kbin, Vbin, Wq, Wk, Wv, Qh, Ql, Kh, Kl, Vb, 8);

  dim3 gscan(NCHUNK, BB * HH);
  scanA_kernel<<<gscan, blk, 0, stream>>>(Kh, Kl, Vb, part, csums, wGp);
  chunk_kernel<<<gscan, blk, 0, stream>>>(Kh, Vb, Qh, Ql, wGp, csums, Abf);

  gemm_bf16<<<dim3(DD / 128, (BB * SS) / 64), blk, 0, stream>>>(Abf, Wo, out, BB * SS, DD, DD);
}

// Round 10
// 142.672 us; speedup vs baseline: 1.5043x; 1.5043x over previous
//
#include <hip/hip_runtime.h>
#include <hip/hip_bf16.h>

// Problem constants
#define BB 2
#define SS 2048
#define GG 16
#define HH 8
#define EE 64
#define DD 512
#define NCHUNK 32
#define CLEN 64
#define CS_STRIDE 132  // 64 sk + 64 sv + 1 n + 3 pad

typedef __attribute__((ext_vector_type(8))) short bf16x8;
typedef __attribute__((ext_vector_type(4))) short s16x4;
typedef __attribute__((ext_vector_type(4))) float f32x4;

static __device__ __forceinline__ short f2bf(float x) {
  union { float f; unsigned u; } v; v.f = x;
  unsigned r = v.u + 0x7fffu + ((v.u >> 16) & 1u);  // round-nearest-even
  return (short)(r >> 16);
}
static __device__ __forceinline__ float bf2f(short s) {
  return __uint_as_float(((unsigned)(unsigned short)s) << 16);
}
static __device__ __forceinline__ void bsplit(float x, short& hi, short& lo) {
  hi = f2bf(x);
  lo = f2bf(x - bf2f(hi));
}

// ---- prep kernel: z<4 weight transpose+cvt; z==4 ctx split-K partials; z>=5 f32->bf16 cvt ----
__global__ __launch_bounds__(256) void prep_kernel(const float* __restrict__ w0,
                                                   const float* __restrict__ w1,
                                                   const float* __restrict__ w2,
                                                   const float* __restrict__ w3,
                                                   short* __restrict__ o0,
                                                   short* __restrict__ o1,
                                                   short* __restrict__ o2,
                                                   short* __restrict__ o3,
                                                   const float* __restrict__ ctxA,
                                                   const float* __restrict__ ctxW,
                                                   float* __restrict__ part,
                                                   const float* __restrict__ qin,
                                                   const float* __restrict__ kin,
                                                   const float* __restrict__ vin,
                                                   short* __restrict__ Qb,
                                                   short* __restrict__ Kb,
                                                   short* __restrict__ Vb) {
  __shared__ float smem[32 * 68 + 64 * 68];
  const int tx = threadIdx.x, ty = threadIdx.y;
  const int tid = ty * 32 + tx;
  if (blockIdx.z < 4) {
    const float* W; short* O;
    if (blockIdx.z == 0)      { W = w0; O = o0; }
    else if (blockIdx.z == 1) { W = w1; O = o1; }
    else if (blockIdx.z == 2) { W = w2; O = o2; }
    else                      { W = w3; O = o3; }
    float (*t)[33] = (float (*)[33])smem;
    const int k0 = blockIdx.x * 32, n0 = blockIdx.y * 32;
#pragma unroll
    for (int i = 0; i < 4; ++i)
      t[ty + i * 8][tx] = W[(size_t)(k0 + ty + i * 8) * DD + n0 + tx];
    __syncthreads();
#pragma unroll
    for (int i = 0; i < 4; ++i)
      O[(size_t)(n0 + ty + i * 8) * DD + k0 + tx] = f2bf(t[tx][ty + i * 8]);
    return;
  }
  if (blockIdx.z >= 5) {
    const float* src; short* dst;
    if (blockIdx.z == 5)      { src = qin; dst = Qb; }
    else if (blockIdx.z == 6) { src = kin; dst = Kb; }
    else                      { src = vin; dst = Vb; }
    const size_t base0 = (size_t)(blockIdx.y * 16 + blockIdx.x) * 8192 + tid * 8;
#pragma unroll
    for (int i = 0; i < 4; ++i) {
      size_t base = base0 + (size_t)i * 2048;
      float4 x0 = *(const float4*)(src + base);
      float4 x1 = *(const float4*)(src + base + 4);
      bf16x8 o;
      o[0] = f2bf(x0.x); o[1] = f2bf(x0.y); o[2] = f2bf(x0.z); o[3] = f2bf(x0.w);
      o[4] = f2bf(x1.x); o[5] = f2bf(x1.y); o[6] = f2bf(x1.z); o[7] = f2bf(x1.w);
      *(bf16x8*)(dst + base) = o;
    }
    return;
  }
  if (blockIdx.x >= 8 || blockIdx.y >= 8) return;
  const int nt = blockIdx.x, ky = blockIdx.y;
  float (*As)[68] = (float (*)[68])smem;
  float (*Ws)[68] = (float (*)[68])(smem + 32 * 68);
  {
    int m = tid >> 3, kq = (tid & 7) * 8;
    float4 a0 = *(const float4*)(ctxA + (size_t)m * DD + ky * 64 + kq);
    float4 a1 = *(const float4*)(ctxA + (size_t)m * DD + ky * 64 + kq + 4);
    As[m][kq + 0] = a0.x; As[m][kq + 1] = a0.y; As[m][kq + 2] = a0.z; As[m][kq + 3] = a0.w;
    As[m][kq + 4] = a1.x; As[m][kq + 5] = a1.y; As[m][kq + 6] = a1.z; As[m][kq + 7] = a1.w;
  }
  {
    int k = tid >> 2, nq = (tid & 3) * 16;
#pragma unroll
    for (int i = 0; i < 4; ++i) {
      float4 wv = *(const float4*)(ctxW + (size_t)(ky * 64 + k) * DD + nt * 64 + nq + i * 4);
      Ws[k][nq + i * 4 + 0] = wv.x; Ws[k][nq + i * 4 + 1] = wv.y;
      Ws[k][nq + i * 4 + 2] = wv.z; Ws[k][nq + i * 4 + 3] = wv.w;
    }
  }
  __syncthreads();
  const int txl = tid & 63, my = tid >> 6;
  float acc[8] = {};
  for (int k = 0; k < 64; ++k) {
    float wv = Ws[k][txl];
#pragma unroll
    for (int m = 0; m < 8; ++m) acc[m] += As[my * 8 + m][k] * wv;
  }
#pragma unroll
  for (int m = 0; m < 8; ++m)
    part[((size_t)ky * 32 + my * 8 + m) * DD + nt * 64 + txl] = acc[m];
}

#define LDA 72

// ---- batched projection GEMM (bf16 A), 64x64 tile, BK=64; hi/lo planes out ----
// 1536 blocks = 6 blocks/CU (was 3) -> 2x latency-hiding TLP (R9 counters:
// MfmaUtil 20%, Occ 30%, HBM 28% => latency-bound at 3 blocks/CU).
__global__ __launch_bounds__(256) void proj_gemm(const short* __restrict__ a0,
                                                 const short* __restrict__ a1,
                                                 const short* __restrict__ a2,
                                                 const short* __restrict__ b0,
                                                 const short* __restrict__ b1,
                                                 const short* __restrict__ b2,
                                                 short* __restrict__ h0,
                                                 short* __restrict__ l0,
                                                 short* __restrict__ h1,
                                                 short* __restrict__ l1,
                                                 short* __restrict__ h2) {
  const short* A; const short* Bt; short* Chi; short* Clo;
  if (blockIdx.z == 0)      { A = a0; Bt = b0; Chi = h0; Clo = l0; }
  else if (blockIdx.z == 1) { A = a1; Bt = b1; Chi = h1; Clo = l1; }
  else                      { A = a2; Bt = b2; Chi = h2; Clo = nullptr; }
  const int N = DD, K = DD;
  __shared__ short As[64 * LDA];
  __shared__ short Bs[64 * LDA];
  const int tid = threadIdx.x;
  const int m0 = blockIdx.y * 64, n0 = blockIdx.x * 64;
  const int wv = tid >> 6, lane = tid & 63;
  const int wm = wv * 16;
  const int r = lane & 15, q = lane >> 4;
  f32x4 acc[4] = {};
  for (int k0 = 0; k0 < K; k0 += 64) {
    bf16x8 av[2], bvv[2];
#pragma unroll
    for (int it = 0; it < 2; ++it) {
      int idx = tid + it * 256;
      int row = idx >> 3, colq = (idx & 7) * 8;
      av[it] = *(const bf16x8*)(A + (size_t)(m0 + row) * K + k0 + colq);
      bvv[it] = *(const bf16x8*)(Bt + (size_t)(n0 + row) * K + k0 + colq);
    }
    __syncthreads();
#pragma unroll
    for (int it = 0; it < 2; ++it) {
      int idx = tid + it * 256;
      int row = idx >> 3, colq = (idx & 7) * 8;
      *(bf16x8*)(&As[row * LDA + colq]) = av[it];
      *(bf16x8*)(&Bs[row * LDA + colq]) = bvv[it];
    }
    __syncthreads();
#pragma unroll
    for (int ks = 0; ks < 2; ++ks) {
      bf16x8 a0r = *(const bf16x8*)(&As[(wm + r) * LDA + ks * 32 + q * 8]);
#pragma unroll
      for (int j = 0; j < 4; ++j) {
        bf16x8 br = *(const bf16x8*)(&Bs[(j * 16 + r) * LDA + ks * 32 + q * 8]);
        acc[j] = __builtin_amdgcn_mfma_f32_16x16x32_bf16(a0r, br, acc[j], 0, 0, 0);
      }
    }
  }
#pragma unroll
  for (int j = 0; j < 4; ++j)
#pragma unroll
    for (int reg = 0; reg < 4; ++reg) {
      int m = m0 + wm + q * 4 + reg;
      int n = n0 + j * 16 + r;
      float x = acc[j][reg];
      short hi = f2bf(x);
      Chi[(size_t)m * N + n] = hi;
      if (Clo) Clo[(size_t)m * N + n] = f2bf(x - bf2f(hi));
    }
}

// ---------------- output GEMM (bf16 A), 64x128 tile, BK=64 ----------------
__global__ __launch_bounds__(256) void gemm_bf16(const short* __restrict__ A,
                                                 const short* __restrict__ Bt,
                                                 float* __restrict__ C,
                                                 int M, int N, int K) {
  __shared__ short As[64 * LDA];
  __shared__ short Bs[128 * LDA];
  const int tid = threadIdx.x;
  const int m0 = blockIdx.y * 64, n0 = blockIdx.x * 128;
  const int wv = tid >> 6, lane = tid & 63;
  const int wm = wv * 16;
  const int r = lane & 15, q = lane >> 4;
  f32x4 acc[8] = {};
  for (int k0 = 0; k0 < K; k0 += 64) {
    bf16x8 av[2], bvv[4];
#pragma unroll
    for (int it = 0; it < 2; ++it) {
      int idx = tid + it * 256;
      int row = idx >> 3, colq = (idx & 7) * 8;
      av[it] = *(const bf16x8*)(A + (size_t)(m0 + row) * K + k0 + colq);
    }
#pragma unroll
    for (int it = 0; it < 4; ++it) {
      int idx = tid + it * 256;
      int row = idx >> 3, colq = (idx & 7) * 8;
      bvv[it] = *(const bf16x8*)(Bt + (size_t)(n0 + row) * K + k0 + colq);
    }
    __syncthreads();
#pragma unroll
    for (int it = 0; it < 2; ++it) {
      int idx = tid + it * 256;
      int row = idx >> 3, colq = (idx & 7) * 8;
      *(bf16x8*)(&As[row * LDA + colq]) = av[it];
    }
#pragma unroll
    for (int it = 0; it < 4; ++it) {
      int idx = tid + it * 256;
      int row = idx >> 3, colq = (idx & 7) * 8;
      *(bf16x8*)(&Bs[row * LDA + colq]) = bvv[it];
    }
    __syncthreads();
#pragma unroll
    for (int ks = 0; ks < 2; ++ks) {
      bf16x8 a0r = *(const bf16x8*)(&As[(wm + r) * LDA + ks * 32 + q * 8]);
#pragma unroll
      for (int j = 0; j < 8; ++j) {
        bf16x8 br = *(const bf16x8*)(&Bs[(j * 16 + r) * LDA + ks * 32 + q * 8]);
        acc[j] = __builtin_amdgcn_mfma_f32_16x16x32_bf16(a0r, br, acc[j], 0, 0, 0);
      }
    }
  }
#pragma unroll
  for (int j = 0; j < 8; ++j)
#pragma unroll
    for (int reg = 0; reg < 4; ++reg) {
      int m = m0 + wm + q * 4 + reg;
      int n = n0 + j * 16 + r;
      C[(size_t)m * N + n] = acc[j][reg];
    }
}

#define LDW 72
#define LDN 40

// ---------------- scan phase A: chunk-local sums via MFMA; also exports w planes ----------------
__global__ __launch_bounds__(256) void scanA_kernel(const short* __restrict__ Kh,
                                                    const short* __restrict__ Kl,
                                                    const short* __restrict__ Vb,
                                                    const float* __restrict__ part,
                                                    float* __restrict__ csums,
                                                    short* __restrict__ wG) {
  const int bh = blockIdx.y, c = blockIdx.x;
  const int b = bh >> 3, h = bh & 7;
  const int tid = threadIdx.x;
  const int lane = tid & 63, wvid = tid >> 6;
  const int r = lane & 15, q = lane >> 4;

  __shared__ short csh[16 * LDW], csl[16 * LDW];
  __shared__ short kh[64 * LDW], kl[64 * LDW];
  __shared__ short kTh[64 * LDW], kTl[64 * LDW];
  __shared__ short vT[64 * LDW];
  __shared__ short wh[16 * LDW], wl[16 * LDW];
  __shared__ float nPart[4][16];

  const int row = tid >> 2, c16 = (tid & 3) * 16;
  const size_t gb = ((size_t)(b * SS + c * CLEN + row)) * DD + h * EE + c16;
  bf16x8 kh0 = *(const bf16x8*)(Kh + gb);
  bf16x8 kh1 = *(const bf16x8*)(Kh + gb + 8);
  bf16x8 kl0 = *(const bf16x8*)(Kl + gb);
  bf16x8 kl1 = *(const bf16x8*)(Kl + gb + 8);
  bf16x8 v0 = *(const bf16x8*)(Vb + gb);
  bf16x8 v1 = *(const bf16x8*)(Vb + gb + 8);
  *(bf16x8*)(&kh[row * LDW + c16]) = kh0;
  *(bf16x8*)(&kh[row * LDW + c16 + 8]) = kh1;
  *(bf16x8*)(&kl[row * LDW + c16]) = kl0;
  *(bf16x8*)(&kl[row * LDW + c16 + 8]) = kl1;
#pragma unroll
  for (int t = 0; t < 8; ++t) {
    kTh[(c16 + t) * LDW + row] = kh0[t];
    kTh[(c16 + 8 + t) * LDW + row] = kh1[t];
    kTl[(c16 + t) * LDW + row] = kl0[t];
    kTl[(c16 + 8 + t) * LDW + row] = kl1[t];
    vT[(c16 + t) * LDW + row] = v0[t];
    vT[(c16 + 8 + t) * LDW + row] = v1[t];
  }
  {
    const int g0 = tid >> 4, t4 = (tid & 15) * 4;
    float4 csv = make_float4(0, 0, 0, 0);
#pragma unroll
    for (int ky = 0; ky < 8; ++ky) {
      float4 p = *(const float4*)(part + ((size_t)(ky * 32 + b * GG + g0)) * DD + h * EE + t4);
      csv.x += p.x; csv.y += p.y; csv.z += p.z; csv.w += p.w;
    }
    const float* pc = (const float*)&csv;
#pragma unroll
    for (int e = 0; e < 4; ++e) {
      short hi, lo;
      bsplit(pc[e], hi, lo);
      csh[g0 * LDW + t4 + e] = hi;
      csl[g0 * LDW + t4 + e] = lo;
    }
  }
  __syncthreads();  // S0

  f32x4 accw = {0.f, 0.f, 0.f, 0.f};
#pragma unroll
  for (int ks = 0; ks < 2; ++ks) {
    bf16x8 ah = *(const bf16x8*)(&csh[r * LDW + ks * 32 + q * 8]);
    bf16x8 al = *(const bf16x8*)(&csl[r * LDW + ks * 32 + q * 8]);
    bf16x8 bh = *(const bf16x8*)(&kh[(wvid * 16 + r) * LDW + ks * 32 + q * 8]);
    bf16x8 bl = *(const bf16x8*)(&kl[(wvid * 16 + r) * LDW + ks * 32 + q * 8]);
    accw = __builtin_amdgcn_mfma_f32_16x16x32_bf16(ah, bh, accw, 0, 0, 0);
    accw = __builtin_amdgcn_mfma_f32_16x16x32_bf16(ah, bl, accw, 0, 0, 0);
    accw = __builtin_amdgcn_mfma_f32_16x16x32_bf16(al, bh, accw, 0, 0, 0);
  }
  const size_t wbase = (size_t)(bh * NCHUNK + c) * 2048;
  float wf[4];
#pragma unroll
  for (int reg = 0; reg < 4; ++reg) {
    wf[reg] = expf(accw[reg] * 0.125f);
    short hi, lo;
    bsplit(wf[reg], hi, lo);
    int g = q * 4 + reg, t = wvid * 16 + r;
    wh[g * LDW + t] = hi;
    wl[g * LDW + t] = lo;
    wG[wbase + g * 64 + t] = hi;          // export w hi plane
    wG[wbase + 1024 + g * 64 + t] = lo;   // export w lo plane
  }
#pragma unroll
  for (int reg = 0; reg < 4; ++reg) {
    float np = wf[reg];
    np += __shfl_xor(np, 1);
    np += __shfl_xor(np, 2);
    np += __shfl_xor(np, 4);
    np += __shfl_xor(np, 8);
    if (r == 0) nPart[wvid][q * 4 + reg] = np;
  }
  __syncthreads();  // S1

  f32x4 ask = {0.f, 0.f, 0.f, 0.f}, asv = ask;
#pragma unroll
  for (int ks = 0; ks < 2; ++ks) {
    bf16x8 awh = *(const bf16x8*)(&wh[r * LDW + ks * 32 + q * 8]);
    bf16x8 awl = *(const bf16x8*)(&wl[r * LDW + ks * 32 + q * 8]);
    bf16x8 bkh = *(const bf16x8*)(&kTh[(wvid * 16 + r) * LDW + ks * 32 + q * 8]);
    bf16x8 bkl = *(const bf16x8*)(&kTl[(wvid * 16 + r) * LDW + ks * 32 + q * 8]);
    bf16x8 bv = *(const bf16x8*)(&vT[(wvid * 16 + r) * LDW + ks * 32 + q * 8]);
    ask = __builtin_amdgcn_mfma_f32_16x16x32_bf16(awh, bkh, ask, 0, 0, 0);
    ask = __builtin_amdgcn_mfma_f32_16x16x32_bf16(awh, bkl, ask, 0, 0, 0);
    ask = __builtin_amdgcn_mfma_f32_16x16x32_bf16(awl, bkh, ask, 0, 0, 0);
    asv = __builtin_amdgcn_mfma_f32_16x16x32_bf16(awh, bv, asv, 0, 0, 0);
    asv = __builtin_amdgcn_mfma_f32_16x16x32_bf16(awl, bv, asv, 0, 0, 0);
  }
#pragma unroll
  for (int reg = 0; reg < 4; ++reg) {
    int g = q * 4 + reg, e = wvid * 16 + r;
    size_t ob = ((size_t)((bh * NCHUNK + c) * GG + g)) * CS_STRIDE;
    csums[ob + e] = ask[reg];
    csums[ob + 64 + e] = asv[reg];
  }
  if (tid < 16) {
    size_t ob = ((size_t)((bh * NCHUNK + c) * GG + tid)) * CS_STRIDE;
    csums[ob + 128] = nPart[0][tid] + nPart[1][tid] + nPart[2][tid] + nPart[3][tid];
  }
}

// ---------------- chunk kernel: causal attention, w loaded (not recomputed) ----------------
__global__ __launch_bounds__(256) void chunk_kernel(const short* __restrict__ Kh,
                                                    const short* __restrict__ Vb,
                                                    const short* __restrict__ Qh,
                                                    const short* __restrict__ Ql,
                                                    const short* __restrict__ wG,
                                                    const float* __restrict__ csums,
                                                    short* __restrict__ attnbf) {
  const int c = blockIdx.x, bh = blockIdx.y;
  const int b = bh >> 3, h = bh & 7;
  const int tid = threadIdx.x;
  const int lane = tid & 63, wvid = tid >> 6;
  const int r = lane & 15, q = lane >> 4;
  const int sw = wvid * 16;

  __shared__ short qh[64 * LDW], qlo[64 * LDW], khb[64 * LDW], dh[64 * LDW];
  __shared__ short whb[16 * LDW], wlb[16 * LDW], skph[16 * LDW], skpl[16 * LDW];
  __shared__ short svpt[64 * LDN];
  __shared__ float nL[16 * 68];
  __shared__ float npreL[16];
  short* wct = qh;   // reused post-B1
  short* cmb = qlo;  // reused post-B1
  short* vt = khb;   // reused post-B1
  short* uh = dh;    // reused post-phase3

  const int row = tid >> 2, c16 = (tid & 3) * 16;
  const size_t gb = ((size_t)(b * SS + c * CLEN + row)) * DD + h * EE + c16;
  bf16x8 q0 = *(const bf16x8*)(Qh + gb);
  bf16x8 q1 = *(const bf16x8*)(Qh + gb + 8);
  bf16x8 ql0 = *(const bf16x8*)(Ql + gb);
  bf16x8 ql1 = *(const bf16x8*)(Ql + gb + 8);
  bf16x8 k0 = *(const bf16x8*)(Kh + gb);
  bf16x8 k1 = *(const bf16x8*)(Kh + gb + 8);
  bf16x8 v0 = *(const bf16x8*)(Vb + gb);
  bf16x8 v1 = *(const bf16x8*)(Vb + gb + 8);
  // w planes (bit-exact values scanA computed)
  const size_t wbase = (size_t)(bh * NCHUNK + c) * 2048;
  s16x4 wh4 = *(const s16x4*)(wG + wbase + tid * 4);
  s16x4 wl4 = *(const s16x4*)(wG + wbase + 1024 + tid * 4);

  const int g0 = tid >> 4, t4 = (tid & 15) * 4;
  float4 skv = make_float4(0, 0, 0, 0), svv = make_float4(0, 0, 0, 0);
  {
    int c2 = 0;
    for (; c2 + 4 <= c; c2 += 4) {
#pragma unroll
      for (int u = 0; u < 4; ++u) {
        size_t ob2 = ((size_t)((bh * NCHUNK + c2 + u) * GG + g0)) * CS_STRIDE;
        float4 a = *(const float4*)(csums + ob2 + t4);
        float4 bsum = *(const float4*)(csums + ob2 + 64 + t4);
        skv.x += a.x; skv.y += a.y; skv.z += a.z; skv.w += a.w;
        svv.x += bsum.x; svv.y += bsum.y; svv.z += bsum.z; svv.w += bsum.w;
      }
    }
    for (; c2 < c; ++c2) {
      size_t ob2 = ((size_t)((bh * NCHUNK + c2) * GG + g0)) * CS_STRIDE;
      float4 a = *(const float4*)(csums + ob2 + t4);
      float4 bsum = *(const float4*)(csums + ob2 + 64 + t4);
      skv.x += a.x; skv.y += a.y; skv.z += a.z; skv.w += a.w;
      svv.x += bsum.x; svv.y += bsum.y; svv.z += bsum.z; svv.w += bsum.w;
    }
  }
  if (tid < 16) {
    float npr = 0.f;
    for (int c2 = 0; c2 < c; ++c2)
      npr += csums[((size_t)((bh * NCHUNK + c2) * GG + tid)) * CS_STRIDE + 128];
    npreL[tid] = npr;
  }

  *(bf16x8*)(&qh[row * LDW + c16]) = q0;
  *(bf16x8*)(&qh[row * LDW + c16 + 8]) = q1;
  *(bf16x8*)(&qlo[row * LDW + c16]) = ql0;
  *(bf16x8*)(&qlo[row * LDW + c16 + 8]) = ql1;
  *(bf16x8*)(&khb[row * LDW + c16]) = k0;
  *(bf16x8*)(&khb[row * LDW + c16 + 8]) = k1;
  {
    // stage w planes: idx = tid*4 -> g = idx>>6, t = idx&63
    int gI = (tid * 4) >> 6, tI = (tid * 4) & 63;
    *(s16x4*)(&whb[gI * LDW + tI]) = wh4;
    *(s16x4*)(&wlb[gI * LDW + tI]) = wl4;
  }
  {
    const float* ps = (const float*)&skv;
#pragma unroll
    for (int e = 0; e < 4; ++e) {
      short hi, lo;
      bsplit(ps[e], hi, lo);
      skph[g0 * LDW + t4 + e] = hi;
      skpl[g0 * LDW + t4 + e] = lo;
    }
  }
  __syncthreads();  // S0

#pragma unroll
  for (int gg = 0; gg < 4; ++gg) {
    int g = wvid * 4 + gg;
    float val = bf2f(whb[g * LDW + lane]) + bf2f(wlb[g * LDW + lane]);
#pragma unroll
    for (int d = 1; d < 64; d <<= 1) {
      float tup = __shfl_up(val, d);
      if (lane >= d) val += tup;
    }
    nL[g * 68 + lane] = npreL[g] + val;
  }

  f32x4 accd[4];
  f32x4 accwt = {0.f, 0.f, 0.f, 0.f};
#pragma unroll
  for (int ct = 0; ct < 4; ++ct) accd[ct] = accwt;
#pragma unroll
  for (int kst = 0; kst < 2; ++kst) {
    bf16x8 aq = *(const bf16x8*)(&qh[(sw + r) * LDW + kst * 32 + q * 8]);
    bf16x8 aql = *(const bf16x8*)(&qlo[(sw + r) * LDW + kst * 32 + q * 8]);
    bf16x8 bsh = *(const bf16x8*)(&skph[r * LDW + kst * 32 + q * 8]);
    bf16x8 bsl = *(const bf16x8*)(&skpl[r * LDW + kst * 32 + q * 8]);
    accwt = __builtin_amdgcn_mfma_f32_16x16x32_bf16(aq, bsh, accwt, 0, 0, 0);
    accwt = __builtin_amdgcn_mfma_f32_16x16x32_bf16(aq, bsl, accwt, 0, 0, 0);
    accwt = __builtin_amdgcn_mfma_f32_16x16x32_bf16(aql, bsh, accwt, 0, 0, 0);
#pragma unroll
    for (int ct = 0; ct < 4; ++ct) {
      bf16x8 bk = *(const bf16x8*)(&khb[(ct * 16 + r) * LDW + kst * 32 + q * 8]);
      accd[ct] = __builtin_amdgcn_mfma_f32_16x16x32_bf16(aq, bk, accd[ct], 0, 0, 0);
    }
  }
#pragma unroll
  for (int ct = 0; ct < 4; ++ct)
#pragma unroll
    for (int reg = 0; reg < 4; ++reg) {
      int sl = sw + q * 4 + reg, tl = ct * 16 + r;
      float v = (tl <= sl) ? accd[ct][reg] : 0.f;
      dh[sl * LDW + tl] = f2bf(v);
    }
  __syncthreads();  // B1

#pragma unroll
  for (int t = 0; t < 8; ++t) {
    vt[(c16 + t) * LDW + row] = v0[t];
    vt[(c16 + 8 + t) * LDW + row] = v1[t];
  }
  {
    const float* pv = (const float*)&svv;
#pragma unroll
    for (int e = 0; e < 4; ++e)
      svpt[(t4 + e) * LDN + g0] = f2bf(pv[e]);
    int ez = tid >> 2, gz = 16 + (tid & 3) * 4;
#pragma unroll
    for (int e = 0; e < 4; ++e) svpt[ez * LDN + gz + e] = 0;
    int tt = tid >> 2, gw = (tid & 3) * 4;
#pragma unroll
    for (int e = 0; e < 4; ++e) {
      wct[tt * LDN + gw + e] = whb[(gw + e) * LDW + tt];
      wct[tt * LDN + 16 + gw + e] = 0;
    }
  }

#pragma unroll
  for (int kst = 0; kst < 2; ++kst) {
    bf16x8 ad = *(const bf16x8*)(&dh[(sw + r) * LDW + kst * 32 + q * 8]);
    bf16x8 bw = *(const bf16x8*)(&whb[r * LDW + kst * 32 + q * 8]);
    bf16x8 bl = *(const bf16x8*)(&wlb[r * LDW + kst * 32 + q * 8]);
    accwt = __builtin_amdgcn_mfma_f32_16x16x32_bf16(ad, bw, accwt, 0, 0, 0);
    accwt = __builtin_amdgcn_mfma_f32_16x16x32_bf16(ad, bl, accwt, 0, 0, 0);
  }
#pragma unroll
  for (int reg = 0; reg < 4; ++reg) {
    int sl = sw + q * 4 + reg;
    float nv = fmaxf(nL[r * 68 + sl], 1e-8f);
    float wt = accwt[reg] / nv;
    float m = wt;
    m = fmaxf(m, __shfl_xor(m, 1));
    m = fmaxf(m, __shfl_xor(m, 2));
    m = fmaxf(m, __shfl_xor(m, 4));
    m = fmaxf(m, __shfl_xor(m, 8));
    float ex = expf(wt - m);
    float den = ex;
    den += __shfl_xor(den, 1);
    den += __shfl_xor(den, 2);
    den += __shfl_xor(den, 4);
    den += __shfl_xor(den, 8);
    float cmv = (ex / den) / nv;
    cmb[sl * LDN + r] = f2bf(cmv);
    cmb[sl * LDN + 16 + r] = 0;
  }
  __syncthreads();  // B2

  bf16x8 acm = *(const bf16x8*)(&cmb[(sw + r) * LDN + q * 8]);
  f32x4 accu[4];
#pragma unroll
  for (int ct = 0; ct < 4; ++ct) accu[ct] = (f32x4){0.f, 0.f, 0.f, 0.f};
#pragma unroll
  for (int ct = 0; ct < 4; ++ct) {
    bf16x8 bwc = *(const bf16x8*)(&wct[(ct * 16 + r) * LDN + q * 8]);
    accu[ct] = __builtin_amdgcn_mfma_f32_16x16x32_bf16(acm, bwc, accu[ct], 0, 0, 0);
  }
#pragma unroll
  for (int ct = 0; ct < 4; ++ct)
#pragma unroll
    for (int reg = 0; reg < 4; ++reg) {
      int sl = sw + q * 4 + reg, tl = ct * 16 + r;
      float v = (tl <= sl) ? accu[ct][reg] : 0.f;
      uh[sl * LDW + tl] = f2bf(v);
    }

  f32x4 acco[4];
#pragma unroll
  for (int et = 0; et < 4; ++et) acco[et] = (f32x4){0.f, 0.f, 0.f, 0.f};
#pragma unroll
  for (int et = 0; et < 4; ++et) {
    bf16x8 bs = *(const bf16x8*)(&svpt[(et * 16 + r) * LDN + q * 8]);
    acco[et] = __builtin_amdgcn_mfma_f32_16x16x32_bf16(acm, bs, acco[et], 0, 0, 0);
  }
#pragma unroll
  for (int kst = 0; kst < 2; ++kst) {
    bf16x8 au = *(const bf16x8*)(&uh[(sw + r) * LDW + kst * 32 + q * 8]);
#pragma unroll
    for (int et = 0; et < 4; ++et) {
      bf16x8 bv = *(const bf16x8*)(&vt[(et * 16 + r) * LDW + kst * 32 + q * 8]);
      acco[et] = __builtin_amdgcn_mfma_f32_16x16x32_bf16(au, bv, acco[et], 0, 0, 0);
    }
  }
#pragma unroll
  for (int et = 0; et < 4; ++et)
#pragma unroll
    for (int reg = 0; reg < 4; ++reg) {
      int sl = sw + q * 4 + reg;
      attnbf[((size_t)(b * SS + c * CLEN + sl)) * DD + h * EE + et * 16 + r] =
          f2bf(acco[et][reg]);
    }
}

extern "C" void kernel_launch(void* const* d_in, const int* in_sizes, int n_in,
                              void* d_out, int out_size, void* d_ws, size_t ws_size,
                              hipStream_t stream) {
  const float* query = (const float*)d_in[0];
  const float* key = (const float*)d_in[1];
  const float* value = (const float*)d_in[2];
  const float* context = (const float*)d_in[3];
  const float* query_proj = (const float*)d_in[4];
  const float* key_proj = (const float*)d_in[5];
  const float* value_proj = (const float*)d_in[6];
  const float* output_proj = (const float*)d_in[7];
  const float* context_proj = (const float*)d_in[8];
  float* out = (float*)d_out;

  const size_t MS = (size_t)BB * SS * DD;  // 2M elements
  const size_t CSN = (size_t)BB * HH * NCHUNK * GG * CS_STRIDE;
  float* fbase = (float*)d_ws;
  float* csums = fbase;                 // 8192*132
  float* part = csums + CSN;            // 8*32*512
  short* Qh = (short*)(part + (size_t)8 * 32 * DD);
  short* Ql = Qh + MS;
  short* Kh = Ql + MS;
  short* Kl = Kh + MS;
  short* Vb = Kl + MS;
  short* Abf = Vb + MS;  // attn bf16
  short* Wq = Abf + MS;
  short* Wk = Wq + (size_t)DD * DD;
  short* Wv = Wk + (size_t)DD * DD;
  short* Wo = Wv + (size_t)DD * DD;
  short* Qbin = Wo + (size_t)DD * DD;   // bf16 raw activations
  short* Kbin = Qbin + MS;
  short* Vbin = Kbin + MS;
  short* wGp = Vbin + MS;               // w hi/lo planes: 512 blocks x 2048 shorts

  dim3 blk(256);
  dim3 tb(32, 8);

  prep_kernel<<<dim3(16, 16, 8), tb, 0, stream>>>(
      query_proj, key_proj, value_proj, output_proj, Wq, Wk, Wv, Wo,
      context, context_proj, part, query, key, value, Qbin, Kbin, Vbin);

  proj_gemm<<<dim3(DD / 64, (BB * SS) / 64, 3), blk, 0, stream>>>(
      Qbin, Kbin, Vbin, Wq, Wk, Wv, Qh, Ql, Kh, Kl, Vb);

  dim3 gscan(NCHUNK, BB * HH);
  scanA_kernel<<<gscan, blk, 0, stream>>>(Kh, Kl, Vb, part, csums, wGp);
  chunk_kernel<<<gscan, blk, 0, stream>>>(Kh, Vb, Qh, Ql, wGp, csums, Abf);

  gemm_bf16<<<dim3(DD / 128, (BB * SS) / 64), blk, 0, stream>>>(Abf, Wo, out, BB * SS, DD, DD);
}

// Round 11
// 139.366 us; speedup vs baseline: 1.5400x; 1.0237x over previous
//
#include <hip/hip_runtime.h>
#include <hip/hip_bf16.h>

// Problem constants
#define BB 2
#define SS 2048
#define GG 16
#define HH 8
#define EE 64
#define DD 512
#define NCHUNK 32
#define CLEN 64
#define CS_STRIDE 132  // 64 sk + 64 sv + 1 n + 3 pad

typedef __attribute__((ext_vector_type(8))) short bf16x8;
typedef __attribute__((ext_vector_type(4))) short s16x4;
typedef __attribute__((ext_vector_type(4))) float f32x4;

static __device__ __forceinline__ short f2bf(float x) {
  union { float f; unsigned u; } v; v.f = x;
  unsigned r = v.u + 0x7fffu + ((v.u >> 16) & 1u);  // round-nearest-even
  return (short)(r >> 16);
}
static __device__ __forceinline__ float bf2f(short s) {
  return __uint_as_float(((unsigned)(unsigned short)s) << 16);
}
static __device__ __forceinline__ void bsplit(float x, short& hi, short& lo) {
  hi = f2bf(x);
  lo = f2bf(x - bf2f(hi));
}

// ---- prep kernel: z<4 weight transpose+cvt; z==4 ctx split-K partials; z>=5 f32->bf16 cvt ----
__global__ __launch_bounds__(256) void prep_kernel(const float* __restrict__ w0,
                                                   const float* __restrict__ w1,
                                                   const float* __restrict__ w2,
                                                   const float* __restrict__ w3,
                                                   short* __restrict__ o0,
                                                   short* __restrict__ o1,
                                                   short* __restrict__ o2,
                                                   short* __restrict__ o3,
                                                   const float* __restrict__ ctxA,
                                                   const float* __restrict__ ctxW,
                                                   float* __restrict__ part,
                                                   const float* __restrict__ qin,
                                                   const float* __restrict__ kin,
                                                   const float* __restrict__ vin,
                                                   short* __restrict__ Qb,
                                                   short* __restrict__ Kb,
                                                   short* __restrict__ Vb) {
  __shared__ float smem[32 * 68 + 64 * 68];
  const int tx = threadIdx.x, ty = threadIdx.y;
  const int tid = ty * 32 + tx;
  if (blockIdx.z < 4) {
    const float* W; short* O;
    if (blockIdx.z == 0)      { W = w0; O = o0; }
    else if (blockIdx.z == 1) { W = w1; O = o1; }
    else if (blockIdx.z == 2) { W = w2; O = o2; }
    else                      { W = w3; O = o3; }
    float (*t)[33] = (float (*)[33])smem;
    const int k0 = blockIdx.x * 32, n0 = blockIdx.y * 32;
#pragma unroll
    for (int i = 0; i < 4; ++i)
      t[ty + i * 8][tx] = W[(size_t)(k0 + ty + i * 8) * DD + n0 + tx];
    __syncthreads();
#pragma unroll
    for (int i = 0; i < 4; ++i)
      O[(size_t)(n0 + ty + i * 8) * DD + k0 + tx] = f2bf(t[tx][ty + i * 8]);
    return;
  }
  if (blockIdx.z >= 5) {
    const float* src; short* dst;
    if (blockIdx.z == 5)      { src = qin; dst = Qb; }
    else if (blockIdx.z == 6) { src = kin; dst = Kb; }
    else                      { src = vin; dst = Vb; }
    const size_t base0 = (size_t)(blockIdx.y * 16 + blockIdx.x) * 8192 + tid * 8;
#pragma unroll
    for (int i = 0; i < 4; ++i) {
      size_t base = base0 + (size_t)i * 2048;
      float4 x0 = *(const float4*)(src + base);
      float4 x1 = *(const float4*)(src + base + 4);
      bf16x8 o;
      o[0] = f2bf(x0.x); o[1] = f2bf(x0.y); o[2] = f2bf(x0.z); o[3] = f2bf(x0.w);
      o[4] = f2bf(x1.x); o[5] = f2bf(x1.y); o[6] = f2bf(x1.z); o[7] = f2bf(x1.w);
      *(bf16x8*)(dst + base) = o;
    }
    return;
  }
  if (blockIdx.x >= 8 || blockIdx.y >= 8) return;
  const int nt = blockIdx.x, ky = blockIdx.y;
  float (*As)[68] = (float (*)[68])smem;
  float (*Ws)[68] = (float (*)[68])(smem + 32 * 68);
  {
    int m = tid >> 3, kq = (tid & 7) * 8;
    float4 a0 = *(const float4*)(ctxA + (size_t)m * DD + ky * 64 + kq);
    float4 a1 = *(const float4*)(ctxA + (size_t)m * DD + ky * 64 + kq + 4);
    As[m][kq + 0] = a0.x; As[m][kq + 1] = a0.y; As[m][kq + 2] = a0.z; As[m][kq + 3] = a0.w;
    As[m][kq + 4] = a1.x; As[m][kq + 5] = a1.y; As[m][kq + 6] = a1.z; As[m][kq + 7] = a1.w;
  }
  {
    int k = tid >> 2, nq = (tid & 3) * 16;
#pragma unroll
    for (int i = 0; i < 4; ++i) {
      float4 wv = *(const float4*)(ctxW + (size_t)(ky * 64 + k) * DD + nt * 64 + nq + i * 4);
      Ws[k][nq + i * 4 + 0] = wv.x; Ws[k][nq + i * 4 + 1] = wv.y;
      Ws[k][nq + i * 4 + 2] = wv.z; Ws[k][nq + i * 4 + 3] = wv.w;
    }
  }
  __syncthreads();
  const int txl = tid & 63, my = tid >> 6;
  float acc[8] = {};
  for (int k = 0; k < 64; ++k) {
    float wv = Ws[k][txl];
#pragma unroll
    for (int m = 0; m < 8; ++m) acc[m] += As[my * 8 + m][k] * wv;
  }
#pragma unroll
  for (int m = 0; m < 8; ++m)
    part[((size_t)ky * 32 + my * 8 + m) * DD + nt * 64 + txl] = acc[m];
}

#define LDA 72

// ---- batched projection GEMM (bf16 A), 64x128 tile, BK=64; hi/lo planes out ----
__global__ __launch_bounds__(256) void proj_gemm(const short* __restrict__ a0,
                                                 const short* __restrict__ a1,
                                                 const short* __restrict__ a2,
                                                 const short* __restrict__ b0,
                                                 const short* __restrict__ b1,
                                                 const short* __restrict__ b2,
                                                 short* __restrict__ h0,
                                                 short* __restrict__ l0,
                                                 short* __restrict__ h1,
                                                 short* __restrict__ l1,
                                                 short* __restrict__ h2) {
  const short* A; const short* Bt; short* Chi; short* Clo;
  if (blockIdx.z == 0)      { A = a0; Bt = b0; Chi = h0; Clo = l0; }
  else if (blockIdx.z == 1) { A = a1; Bt = b1; Chi = h1; Clo = l1; }
  else                      { A = a2; Bt = b2; Chi = h2; Clo = nullptr; }
  const int N = DD, K = DD;
  __shared__ short As[64 * LDA];
  __shared__ short Bs[128 * LDA];
  const int tid = threadIdx.x;
  const int m0 = blockIdx.y * 64, n0 = blockIdx.x * 128;
  const int wv = tid >> 6, lane = tid & 63;
  const int wm = wv * 16;
  const int r = lane & 15, q = lane >> 4;
  f32x4 acc[8] = {};
  for (int k0 = 0; k0 < K; k0 += 64) {
    bf16x8 av[2], bvv[4];
#pragma unroll
    for (int it = 0; it < 2; ++it) {
      int idx = tid + it * 256;
      int row = idx >> 3, colq = (idx & 7) * 8;
      av[it] = *(const bf16x8*)(A + (size_t)(m0 + row) * K + k0 + colq);
    }
#pragma unroll
    for (int it = 0; it < 4; ++it) {
      int idx = tid + it * 256;
      int row = idx >> 3, colq = (idx & 7) * 8;
      bvv[it] = *(const bf16x8*)(Bt + (size_t)(n0 + row) * K + k0 + colq);
    }
    __syncthreads();
#pragma unroll
    for (int it = 0; it < 2; ++it) {
      int idx = tid + it * 256;
      int row = idx >> 3, colq = (idx & 7) * 8;
      *(bf16x8*)(&As[row * LDA + colq]) = av[it];
    }
#pragma unroll
    for (int it = 0; it < 4; ++it) {
      int idx = tid + it * 256;
      int row = idx >> 3, colq = (idx & 7) * 8;
      *(bf16x8*)(&Bs[row * LDA + colq]) = bvv[it];
    }
    __syncthreads();
#pragma unroll
    for (int ks = 0; ks < 2; ++ks) {
      bf16x8 a0r = *(const bf16x8*)(&As[(wm + r) * LDA + ks * 32 + q * 8]);
#pragma unroll
      for (int j = 0; j < 8; ++j) {
        bf16x8 br = *(const bf16x8*)(&Bs[(j * 16 + r) * LDA + ks * 32 + q * 8]);
        acc[j] = __builtin_amdgcn_mfma_f32_16x16x32_bf16(a0r, br, acc[j], 0, 0, 0);
      }
    }
  }
#pragma unroll
  for (int j = 0; j < 8; ++j)
#pragma unroll
    for (int reg = 0; reg < 4; ++reg) {
      int m = m0 + wm + q * 4 + reg;
      int n = n0 + j * 16 + r;
      float x = acc[j][reg];
      short hi = f2bf(x);
      Chi[(size_t)m * N + n] = hi;
      if (Clo) Clo[(size_t)m * N + n] = f2bf(x - bf2f(hi));
    }
}

// ---------------- output GEMM (bf16 A), 64x128 tile, BK=64 ----------------
__global__ __launch_bounds__(256) void gemm_bf16(const short* __restrict__ A,
                                                 const short* __restrict__ Bt,
                                                 float* __restrict__ C,
                                                 int M, int N, int K) {
  __shared__ short As[64 * LDA];
  __shared__ short Bs[128 * LDA];
  const int tid = threadIdx.x;
  const int m0 = blockIdx.y * 64, n0 = blockIdx.x * 128;
  const int wv = tid >> 6, lane = tid & 63;
  const int wm = wv * 16;
  const int r = lane & 15, q = lane >> 4;
  f32x4 acc[8] = {};
  for (int k0 = 0; k0 < K; k0 += 64) {
    bf16x8 av[2], bvv[4];
#pragma unroll
    for (int it = 0; it < 2; ++it) {
      int idx = tid + it * 256;
      int row = idx >> 3, colq = (idx & 7) * 8;
      av[it] = *(const bf16x8*)(A + (size_t)(m0 + row) * K + k0 + colq);
    }
#pragma unroll
    for (int it = 0; it < 4; ++it) {
      int idx = tid + it * 256;
      int row = idx >> 3, colq = (idx & 7) * 8;
      bvv[it] = *(const bf16x8*)(Bt + (size_t)(n0 + row) * K + k0 + colq);
    }
    __syncthreads();
#pragma unroll
    for (int it = 0; it < 2; ++it) {
      int idx = tid + it * 256;
      int row = idx >> 3, colq = (idx & 7) * 8;
      *(bf16x8*)(&As[row * LDA + colq]) = av[it];
    }
#pragma unroll
    for (int it = 0; it < 4; ++it) {
      int idx = tid + it * 256;
      int row = idx >> 3, colq = (idx & 7) * 8;
      *(bf16x8*)(&Bs[row * LDA + colq]) = bvv[it];
    }
    __syncthreads();
#pragma unroll
    for (int ks = 0; ks < 2; ++ks) {
      bf16x8 a0r = *(const bf16x8*)(&As[(wm + r) * LDA + ks * 32 + q * 8]);
#pragma unroll
      for (int j = 0; j < 8; ++j) {
        bf16x8 br = *(const bf16x8*)(&Bs[(j * 16 + r) * LDA + ks * 32 + q * 8]);
        acc[j] = __builtin_amdgcn_mfma_f32_16x16x32_bf16(a0r, br, acc[j], 0, 0, 0);
      }
    }
  }
#pragma unroll
  for (int j = 0; j < 8; ++j)
#pragma unroll
    for (int reg = 0; reg < 4; ++reg) {
      int m = m0 + wm + q * 4 + reg;
      int n = n0 + j * 16 + r;
      C[(size_t)m * N + n] = acc[j][reg];
    }
}

#define LDW 72
#define LDN 40

// ---------------- scan phase A: chunk-local sums via MFMA; also exports w planes ----------------
__global__ __launch_bounds__(256) void scanA_kernel(const short* __restrict__ Kh,
                                                    const short* __restrict__ Kl,
                                                    const short* __restrict__ Vb,
                                                    const float* __restrict__ part,
                                                    float* __restrict__ csums,
                                                    short* __restrict__ wG) {
  const int bh = blockIdx.y, c = blockIdx.x;
  const int b = bh >> 3, h = bh & 7;
  const int tid = threadIdx.x;
  const int lane = tid & 63, wvid = tid >> 6;
  const int r = lane & 15, q = lane >> 4;

  __shared__ short csh[16 * LDW], csl[16 * LDW];
  __shared__ short kh[64 * LDW], kl[64 * LDW];
  __shared__ short kTh[64 * LDW], kTl[64 * LDW];
  __shared__ short vT[64 * LDW];
  __shared__ short wh[16 * LDW], wl[16 * LDW];
  __shared__ float nPart[4][16];

  const int row = tid >> 2, c16 = (tid & 3) * 16;
  const size_t gb = ((size_t)(b * SS + c * CLEN + row)) * DD + h * EE + c16;
  bf16x8 kh0 = *(const bf16x8*)(Kh + gb);
  bf16x8 kh1 = *(const bf16x8*)(Kh + gb + 8);
  bf16x8 kl0 = *(const bf16x8*)(Kl + gb);
  bf16x8 kl1 = *(const bf16x8*)(Kl + gb + 8);
  bf16x8 v0 = *(const bf16x8*)(Vb + gb);
  bf16x8 v1 = *(const bf16x8*)(Vb + gb + 8);
  *(bf16x8*)(&kh[row * LDW + c16]) = kh0;
  *(bf16x8*)(&kh[row * LDW + c16 + 8]) = kh1;
  *(bf16x8*)(&kl[row * LDW + c16]) = kl0;
  *(bf16x8*)(&kl[row * LDW + c16 + 8]) = kl1;
#pragma unroll
  for (int t = 0; t < 8; ++t) {
    kTh[(c16 + t) * LDW + row] = kh0[t];
    kTh[(c16 + 8 + t) * LDW + row] = kh1[t];
    kTl[(c16 + t) * LDW + row] = kl0[t];
    kTl[(c16 + 8 + t) * LDW + row] = kl1[t];
    vT[(c16 + t) * LDW + row] = v0[t];
    vT[(c16 + 8 + t) * LDW + row] = v1[t];
  }
  {
    const int g0 = tid >> 4, t4 = (tid & 15) * 4;
    float4 csv = make_float4(0, 0, 0, 0);
#pragma unroll
    for (int ky = 0; ky < 8; ++ky) {
      float4 p = *(const float4*)(part + ((size_t)(ky * 32 + b * GG + g0)) * DD + h * EE + t4);
      csv.x += p.x; csv.y += p.y; csv.z += p.z; csv.w += p.w;
    }
    const float* pc = (const float*)&csv;
#pragma unroll
    for (int e = 0; e < 4; ++e) {
      short hi, lo;
      bsplit(pc[e], hi, lo);
      csh[g0 * LDW + t4 + e] = hi;
      csl[g0 * LDW + t4 + e] = lo;
    }
  }
  __syncthreads();  // S0

  f32x4 accw = {0.f, 0.f, 0.f, 0.f};
#pragma unroll
  for (int ks = 0; ks < 2; ++ks) {
    bf16x8 ah = *(const bf16x8*)(&csh[r * LDW + ks * 32 + q * 8]);
    bf16x8 al = *(const bf16x8*)(&csl[r * LDW + ks * 32 + q * 8]);
    bf16x8 bh = *(const bf16x8*)(&kh[(wvid * 16 + r) * LDW + ks * 32 + q * 8]);
    bf16x8 bl = *(const bf16x8*)(&kl[(wvid * 16 + r) * LDW + ks * 32 + q * 8]);
    accw = __builtin_amdgcn_mfma_f32_16x16x32_bf16(ah, bh, accw, 0, 0, 0);
    accw = __builtin_amdgcn_mfma_f32_16x16x32_bf16(ah, bl, accw, 0, 0, 0);
    accw = __builtin_amdgcn_mfma_f32_16x16x32_bf16(al, bh, accw, 0, 0, 0);
  }
  const size_t wbase = (size_t)(bh * NCHUNK + c) * 2048;
  float wf[4];
#pragma unroll
  for (int reg = 0; reg < 4; ++reg) {
    wf[reg] = expf(accw[reg] * 0.125f);
    short hi, lo;
    bsplit(wf[reg], hi, lo);
    int g = q * 4 + reg, t = wvid * 16 + r;
    wh[g * LDW + t] = hi;
    wl[g * LDW + t] = lo;
    wG[wbase + g * 64 + t] = hi;          // export w hi plane
    wG[wbase + 1024 + g * 64 + t] = lo;   // export w lo plane
  }
#pragma unroll
  for (int reg = 0; reg < 4; ++reg) {
    float np = wf[reg];
    np += __shfl_xor(np, 1);
    np += __shfl_xor(np, 2);
    np += __shfl_xor(np, 4);
    np += __shfl_xor(np, 8);
    if (r == 0) nPart[wvid][q * 4 + reg] = np;
  }
  __syncthreads();  // S1

  f32x4 ask = {0.f, 0.f, 0.f, 0.f}, asv = ask;
#pragma unroll
  for (int ks = 0; ks < 2; ++ks) {
    bf16x8 awh = *(const bf16x8*)(&wh[r * LDW + ks * 32 + q * 8]);
    bf16x8 awl = *(const bf16x8*)(&wl[r * LDW + ks * 32 + q * 8]);
    bf16x8 bkh = *(const bf16x8*)(&kTh[(wvid * 16 + r) * LDW + ks * 32 + q * 8]);
    bf16x8 bkl = *(const bf16x8*)(&kTl[(wvid * 16 + r) * LDW + ks * 32 + q * 8]);
    bf16x8 bv = *(const bf16x8*)(&vT[(wvid * 16 + r) * LDW + ks * 32 + q * 8]);
    ask = __builtin_amdgcn_mfma_f32_16x16x32_bf16(awh, bkh, ask, 0, 0, 0);
    ask = __builtin_amdgcn_mfma_f32_16x16x32_bf16(awh, bkl, ask, 0, 0, 0);
    ask = __builtin_amdgcn_mfma_f32_16x16x32_bf16(awl, bkh, ask, 0, 0, 0);
    asv = __builtin_amdgcn_mfma_f32_16x16x32_bf16(awh, bv, asv, 0, 0, 0);
    asv = __builtin_amdgcn_mfma_f32_16x16x32_bf16(awl, bv, asv, 0, 0, 0);
  }
#pragma unroll
  for (int reg = 0; reg < 4; ++reg) {
    int g = q * 4 + reg, e = wvid * 16 + r;
    size_t ob = ((size_t)((bh * NCHUNK + c) * GG + g)) * CS_STRIDE;
    csums[ob + e] = ask[reg];
    csums[ob + 64 + e] = asv[reg];
  }
  if (tid < 16) {
    size_t ob = ((size_t)((bh * NCHUNK + c) * GG + tid)) * CS_STRIDE;
    csums[ob + 128] = nPart[0][tid] + nPart[1][tid] + nPart[2][tid] + nPart[3][tid];
  }
}

// ---------------- chunk kernel: causal attention, w loaded (not recomputed) ----------------
__global__ __launch_bounds__(256) void chunk_kernel(const short* __restrict__ Kh,
                                                    const short* __restrict__ Vb,
                                                    const short* __restrict__ Qh,
                                                    const short* __restrict__ Ql,
                                                    const short* __restrict__ wG,
                                                    const float* __restrict__ csums,
                                                    short* __restrict__ attnbf) {
  const int c = blockIdx.x, bh = blockIdx.y;
  const int b = bh >> 3, h = bh & 7;
  const int tid = threadIdx.x;
  const int lane = tid & 63, wvid = tid >> 6;
  const int r = lane & 15, q = lane >> 4;
  const int sw = wvid * 16;

  __shared__ short qh[64 * LDW], qlo[64 * LDW], khb[64 * LDW], dh[64 * LDW];
  __shared__ short whb[16 * LDW], wlb[16 * LDW], skph[16 * LDW], skpl[16 * LDW];
  __shared__ short svpt[64 * LDN];
  __shared__ float nL[16 * 68];
  __shared__ float npreL[16];
  short* wct = qh;   // reused post-B1
  short* cmb = qlo;  // reused post-B1
  short* vt = khb;   // reused post-B1
  short* uh = dh;    // reused post-phase3

  const int row = tid >> 2, c16 = (tid & 3) * 16;
  const size_t gb = ((size_t)(b * SS + c * CLEN + row)) * DD + h * EE + c16;
  bf16x8 q0 = *(const bf16x8*)(Qh + gb);
  bf16x8 q1 = *(const bf16x8*)(Qh + gb + 8);
  bf16x8 ql0 = *(const bf16x8*)(Ql + gb);
  bf16x8 ql1 = *(const bf16x8*)(Ql + gb + 8);
  bf16x8 k0 = *(const bf16x8*)(Kh + gb);
  bf16x8 k1 = *(const bf16x8*)(Kh + gb + 8);
  bf16x8 v0 = *(const bf16x8*)(Vb + gb);
  bf16x8 v1 = *(const bf16x8*)(Vb + gb + 8);
  // w planes (bit-exact values scanA computed)
  const size_t wbase = (size_t)(bh * NCHUNK + c) * 2048;
  s16x4 wh4 = *(const s16x4*)(wG + wbase + tid * 4);
  s16x4 wl4 = *(const s16x4*)(wG + wbase + 1024 + tid * 4);

  const int g0 = tid >> 4, t4 = (tid & 15) * 4;
  float4 skv = make_float4(0, 0, 0, 0), svv = make_float4(0, 0, 0, 0);
  {
    int c2 = 0;
    for (; c2 + 4 <= c; c2 += 4) {
#pragma unroll
      for (int u = 0; u < 4; ++u) {
        size_t ob2 = ((size_t)((bh * NCHUNK + c2 + u) * GG + g0)) * CS_STRIDE;
        float4 a = *(const float4*)(csums + ob2 + t4);
        float4 bsum = *(const float4*)(csums + ob2 + 64 + t4);
        skv.x += a.x; skv.y += a.y; skv.z += a.z; skv.w += a.w;
        svv.x += bsum.x; svv.y += bsum.y; svv.z += bsum.z; svv.w += bsum.w;
      }
    }
    for (; c2 < c; ++c2) {
      size_t ob2 = ((size_t)((bh * NCHUNK + c2) * GG + g0)) * CS_STRIDE;
      float4 a = *(const float4*)(csums + ob2 + t4);
      float4 bsum = *(const float4*)(csums + ob2 + 64 + t4);
      skv.x += a.x; skv.y += a.y; skv.z += a.z; skv.w += a.w;
      svv.x += bsum.x; svv.y += bsum.y; svv.z += bsum.z; svv.w += bsum.w;
    }
  }
  if (tid < 16) {
    float npr = 0.f;
    for (int c2 = 0; c2 < c; ++c2)
      npr += csums[((size_t)((bh * NCHUNK + c2) * GG + tid)) * CS_STRIDE + 128];
    npreL[tid] = npr;
  }

  *(bf16x8*)(&qh[row * LDW + c16]) = q0;
  *(bf16x8*)(&qh[row * LDW + c16 + 8]) = q1;
  *(bf16x8*)(&qlo[row * LDW + c16]) = ql0;
  *(bf16x8*)(&qlo[row * LDW + c16 + 8]) = ql1;
  *(bf16x8*)(&khb[row * LDW + c16]) = k0;
  *(bf16x8*)(&khb[row * LDW + c16 + 8]) = k1;
  {
    // stage w planes: idx = tid*4 -> g = idx>>6, t = idx&63
    int gI = (tid * 4) >> 6, tI = (tid * 4) & 63;
    *(s16x4*)(&whb[gI * LDW + tI]) = wh4;
    *(s16x4*)(&wlb[gI * LDW + tI]) = wl4;
  }
  {
    const float* ps = (const float*)&skv;
#pragma unroll
    for (int e = 0; e < 4; ++e) {
      short hi, lo;
      bsplit(ps[e], hi, lo);
      skph[g0 * LDW + t4 + e] = hi;
      skpl[g0 * LDW + t4 + e] = lo;
    }
  }
  __syncthreads();  // S0

#pragma unroll
  for (int gg = 0; gg < 4; ++gg) {
    int g = wvid * 4 + gg;
    float val = bf2f(whb[g * LDW + lane]) + bf2f(wlb[g * LDW + lane]);
#pragma unroll
    for (int d = 1; d < 64; d <<= 1) {
      float tup = __shfl_up(val, d);
      if (lane >= d) val += tup;
    }
    nL[g * 68 + lane] = npreL[g] + val;
  }

  f32x4 accd[4];
  f32x4 accwt = {0.f, 0.f, 0.f, 0.f};
#pragma unroll
  for (int ct = 0; ct < 4; ++ct) accd[ct] = accwt;
#pragma unroll
  for (int kst = 0; kst < 2; ++kst) {
    bf16x8 aq = *(const bf16x8*)(&qh[(sw + r) * LDW + kst * 32 + q * 8]);
    bf16x8 aql = *(const bf16x8*)(&qlo[(sw + r) * LDW + kst * 32 + q * 8]);
    bf16x8 bsh = *(const bf16x8*)(&skph[r * LDW + kst * 32 + q * 8]);
    bf16x8 bsl = *(const bf16x8*)(&skpl[r * LDW + kst * 32 + q * 8]);
    accwt = __builtin_amdgcn_mfma_f32_16x16x32_bf16(aq, bsh, accwt, 0, 0, 0);
    accwt = __builtin_amdgcn_mfma_f32_16x16x32_bf16(aq, bsl, accwt, 0, 0, 0);
    accwt = __builtin_amdgcn_mfma_f32_16x16x32_bf16(aql, bsh, accwt, 0, 0, 0);
#pragma unroll
    for (int ct = 0; ct < 4; ++ct) {
      bf16x8 bk = *(const bf16x8*)(&khb[(ct * 16 + r) * LDW + kst * 32 + q * 8]);
      accd[ct] = __builtin_amdgcn_mfma_f32_16x16x32_bf16(aq, bk, accd[ct], 0, 0, 0);
    }
  }
#pragma unroll
  for (int ct = 0; ct < 4; ++ct)
#pragma unroll
    for (int reg = 0; reg < 4; ++reg) {
      int sl = sw + q * 4 + reg, tl = ct * 16 + r;
      float v = (tl <= sl) ? accd[ct][reg] : 0.f;
      dh[sl * LDW + tl] = f2bf(v);
    }
  __syncthreads();  // B1

#pragma unroll
  for (int t = 0; t < 8; ++t) {
    vt[(c16 + t) * LDW + row] = v0[t];
    vt[(c16 + 8 + t) * LDW + row] = v1[t];
  }
  {
    const float* pv = (const float*)&svv;
#pragma unroll
    for (int e = 0; e < 4; ++e)
      svpt[(t4 + e) * LDN + g0] = f2bf(pv[e]);
    int ez = tid >> 2, gz = 16 + (tid & 3) * 4;
#pragma unroll
    for (int e = 0; e < 4; ++e) svpt[ez * LDN + gz + e] = 0;
    int tt = tid >> 2, gw = (tid & 3) * 4;
#pragma unroll
    for (int e = 0; e < 4; ++e) {
      wct[tt * LDN + gw + e] = whb[(gw + e) * LDW + tt];
      wct[tt * LDN + 16 + gw + e] = 0;
    }
  }

#pragma unroll
  for (int kst = 0; kst < 2; ++kst) {
    bf16x8 ad = *(const bf16x8*)(&dh[(sw + r) * LDW + kst * 32 + q * 8]);
    bf16x8 bw = *(const bf16x8*)(&whb[r * LDW + kst * 32 + q * 8]);
    bf16x8 bl = *(const bf16x8*)(&wlb[r * LDW + kst * 32 + q * 8]);
    accwt = __builtin_amdgcn_mfma_f32_16x16x32_bf16(ad, bw, accwt, 0, 0, 0);
    accwt = __builtin_amdgcn_mfma_f32_16x16x32_bf16(ad, bl, accwt, 0, 0, 0);
  }
#pragma unroll
  for (int reg = 0; reg < 4; ++reg) {
    int sl = sw + q * 4 + reg;
    float nv = fmaxf(nL[r * 68 + sl], 1e-8f);
    float wt = accwt[reg] / nv;
    float m = wt;
    m = fmaxf(m, __shfl_xor(m, 1));
    m = fmaxf(m, __shfl_xor(m, 2));
    m = fmaxf(m, __shfl_xor(m, 4));
    m = fmaxf(m, __shfl_xor(m, 8));
    float ex = expf(wt - m);
    float den = ex;
    den += __shfl_xor(den, 1);
    den += __shfl_xor(den, 2);
    den += __shfl_xor(den, 4);
    den += __shfl_xor(den, 8);
    float cmv = (ex / den) / nv;
    cmb[sl * LDN + r] = f2bf(cmv);
    cmb[sl * LDN + 16 + r] = 0;
  }
  __syncthreads();  // B2

  bf16x8 acm = *(const bf16x8*)(&cmb[(sw + r) * LDN + q * 8]);
  f32x4 accu[4];
#pragma unroll
  for (int ct = 0; ct < 4; ++ct) accu[ct] = (f32x4){0.f, 0.f, 0.f, 0.f};
#pragma unroll
  for (int ct = 0; ct < 4; ++ct) {
    bf16x8 bwc = *(const bf16x8*)(&wct[(ct * 16 + r) * LDN + q * 8]);
    accu[ct] = __builtin_amdgcn_mfma_f32_16x16x32_bf16(acm, bwc, accu[ct], 0, 0, 0);
  }
#pragma unroll
  for (int ct = 0; ct < 4; ++ct)
#pragma unroll
    for (int reg = 0; reg < 4; ++reg) {
      int sl = sw + q * 4 + reg, tl = ct * 16 + r;
      float v = (tl <= sl) ? accu[ct][reg] : 0.f;
      uh[sl * LDW + tl] = f2bf(v);
    }

  f32x4 acco[4];
#pragma unroll
  for (int et = 0; et < 4; ++et) acco[et] = (f32x4){0.f, 0.f, 0.f, 0.f};
#pragma unroll
  for (int et = 0; et < 4; ++et) {
    bf16x8 bs = *(const bf16x8*)(&svpt[(et * 16 + r) * LDN + q * 8]);
    acco[et] = __builtin_amdgcn_mfma_f32_16x16x32_bf16(acm, bs, acco[et], 0, 0, 0);
  }
#pragma unroll
  for (int kst = 0; kst < 2; ++kst) {
    bf16x8 au = *(const bf16x8*)(&uh[(sw + r) * LDW + kst * 32 + q * 8]);
#pragma unroll
    for (int et = 0; et < 4; ++et) {
      bf16x8 bv = *(const bf16x8*)(&vt[(et * 16 + r) * LDW + kst * 32 + q * 8]);
      acco[et] = __builtin_amdgcn_mfma_f32_16x16x32_bf16(au, bv, acco[et], 0, 0, 0);
    }
  }
#pragma unroll
  for (int et = 0; et < 4; ++et)
#pragma unroll
    for (int reg = 0; reg < 4; ++reg) {
      int sl = sw + q * 4 + reg;
      attnbf[((size_t)(b * SS + c * CLEN + sl)) * DD + h * EE + et * 16 + r] =
          f2bf(acco[et][reg]);
    }
}

extern "C" void kernel_launch(void* const* d_in, const int* in_sizes, int n_in,
                              void* d_out, int out_size, void* d_ws, size_t ws_size,
                              hipStream_t stream) {
  const float* query = (const float*)d_in[0];
  const float* key = (const float*)d_in[1];
  const float* value = (const float*)d_in[2];
  const float* context = (const float*)d_in[3];
  const float* query_proj = (const float*)d_in[4];
  const float* key_proj = (const float*)d_in[5];
  const float* value_proj = (const float*)d_in[6];
  const float* output_proj = (const float*)d_in[7];
  const float* context_proj = (const float*)d_in[8];
  float* out = (float*)d_out;

  const size_t MS = (size_t)BB * SS * DD;  // 2M elements
  const size_t CSN = (size_t)BB * HH * NCHUNK * GG * CS_STRIDE;
  float* fbase = (float*)d_ws;
  float* csums = fbase;                 // 8192*132
  float* part = csums + CSN;            // 8*32*512
  short* Qh = (short*)(part + (size_t)8 * 32 * DD);
  short* Ql = Qh + MS;
  short* Kh = Ql + MS;
  short* Kl = Kh + MS;
  short* Vb = Kl + MS;
  short* Abf = Vb + MS;  // attn bf16
  short* Wq = Abf + MS;
  short* Wk = Wq + (size_t)DD * DD;
  short* Wv = Wk + (size_t)DD * DD;
  short* Wo = Wv + (size_t)DD * DD;
  short* Qbin = Wo + (size_t)DD * DD;   // bf16 raw activations
  short* Kbin = Qbin + MS;
  short* Vbin = Kbin + MS;
  short* wGp = Vbin + MS;               // w hi/lo planes: 512 blocks x 2048 shorts

  dim3 blk(256);
  dim3 tb(32, 8);

  prep_kernel<<<dim3(16, 16, 8), tb, 0, stream>>>(
      query_proj, key_proj, value_proj, output_proj, Wq, Wk, Wv, Wo,
      context, context_proj, part, query, key, value, Qbin, Kbin, Vbin);

  proj_gemm<<<dim3(DD / 128, (BB * SS) / 64, 3), blk, 0, stream>>>(
      Qbin, Kbin, Vbin, Wq, Wk, Wv, Qh, Ql, Kh, Kl, Vb);

  dim3 gscan(NCHUNK, BB * HH);
  scanA_kernel<<<gscan, blk, 0, stream>>>(Kh, Kl, Vb, part, csums, wGp);
  chunk_kernel<<<gscan, blk, 0, stream>>>(Kh, Vb, Qh, Ql, wGp, csums, Abf);

  gemm_bf16<<<dim3(DD / 128, (BB * SS) / 64), blk, 0, stream>>>(Abf, Wo, out, BB * SS, DD, DD);
}